// Round 10
// baseline (896.648 us; speedup 1.0000x reference)
//
#include <hip/hip_runtime.h>
#include <hip/hip_cooperative_groups.h>
#include <cstdint>
#include <cstddef>
#include <utility>

namespace cg = cooperative_groups;

#define PI_F 3.14159265358979323846f

typedef __attribute__((ext_vector_type(8))) _Float16 half8;
typedef __attribute__((ext_vector_type(4))) float f32x4;

struct U4 { unsigned int w[4]; };

static __device__ __forceinline__ unsigned int packhalf2(float c, float s) {
  _Float16 hc = (_Float16)c, hs = (_Float16)s;
  unsigned short uc = __builtin_bit_cast(unsigned short, hc);
  unsigned short us = __builtin_bit_cast(unsigned short, hs);
  return (unsigned int)uc | ((unsigned int)us << 16);
}

static __device__ __forceinline__ void load16_lds(const void* g, void* l) {
  __builtin_amdgcn_global_load_lds(
      (const __attribute__((address_space(1))) unsigned int*)g,
      (__attribute__((address_space(3))) unsigned int*)l, 16, 0, 0);
}

// ---------------------------------------------------------------------------
// K1: MLP for all 2B samples -> hz[sample][16] = {h[0..7], z[0..6], 0}.
// Block 0 thread 0 also zero-inits scalars + out.
// ---------------------------------------------------------------------------
__global__ __launch_bounds__(256) void k_mlp(
    const float* __restrict__ x1, const float* __restrict__ x0,
    const float* __restrict__ W1, const float* __restrict__ b1,
    const float* __restrict__ W2, const float* __restrict__ b2,
    const float* __restrict__ W3, const float* __restrict__ b3,
    float* __restrict__ hz, int B, float* __restrict__ scalars,
    float* __restrict__ out) {
  int s = blockIdx.x * blockDim.x + threadIdx.x;
  if (blockIdx.x == 0 && threadIdx.x == 0) {
    scalars[0] = 0.f;
    scalars[1] = 0.f;
    out[0] = 0.f;
  }
  if (s >= 2 * B) return;
  const float* xp = (s < B) ? (x1 + (size_t)s * 8) : (x0 + (size_t)(s - B) * 8);
  float x[8];
#pragma unroll
  for (int k = 0; k < 8; k++) x[k] = xp[k];
  float a1[10];
#pragma unroll
  for (int o = 0; o < 10; o++) {
    float v = b1[o];
#pragma unroll
    for (int k = 0; k < 8; k++) v = fmaf(W1[o * 8 + k], x[k], v);
    a1[o] = fmaxf(v, 0.f);
  }
  float a2[10];
#pragma unroll
  for (int o = 0; o < 10; o++) {
    float v = b2[o];
#pragma unroll
    for (int k = 0; k < 10; k++) v = fmaf(W2[o * 10 + k], a1[k], v);
    a2[o] = fmaxf(v, 0.f);
  }
  float h[8];
#pragma unroll
  for (int o = 0; o < 8; o++) {
    float v = b3[o];
#pragma unroll
    for (int k = 0; k < 10; k++) v = fmaf(W3[o * 10 + k], a2[k], v);
    h[o] = v;
  }
  float outv[16];
#pragma unroll
  for (int k = 0; k < 8; k++) outv[k] = h[k];
#pragma unroll
  for (int k = 0; k < 7; k++) outv[8 + k] = (PI_F - h[k]) * (PI_F - h[k + 1]);
  outv[15] = 0.f;
  float4* dst = (float4*)(hz + (size_t)s * 16);
#pragma unroll
  for (int q = 0; q < 4; q++) dst[q] = ((float4*)outv)[q];
}

// ---------------------------------------------------------------------------
// K2: generate fp16 (cos,sin) pairs. A layout: [kb][256 rows][64 halfs],
// 16B chunks XOR-swizzled by (row&7). Gray-code walk + HW v_sin/v_cos.
// ---------------------------------------------------------------------------
__global__ __launch_bounds__(256) void k_gen(const float* __restrict__ hz,
                                             _Float16* __restrict__ Ach) {
  __shared__ float hzl[32][17];
  int kb = blockIdx.x, t = threadIdx.x;
  if (t < 128) {
    int smp = t >> 2, q = t & 3;
    const float4 v =
        *(const float4*)(hz + (size_t)(kb * 32 + smp) * 16 + q * 4);
    hzl[smp][q * 4 + 0] = v.x;
    hzl[smp][q * 4 + 1] = v.y;
    hzl[smp][q * 4 + 2] = v.z;
    hzl[smp][q * 4 + 3] = v.w;
  }
  __syncthreads();
  int s = t & 31, oct = t >> 5;
  float h[8], z[7];
#pragma unroll
  for (int k = 0; k < 8; k++) h[k] = hzl[s][k];
#pragma unroll
  for (int k = 0; k < 7; k++) z[k] = hzl[s][8 + k];
  float S5 = (oct & 4) ? -1.f : 1.f;
  float S6 = (oct & 2) ? -1.f : 1.f;
  float S7 = (oct & 1) ? -1.f : 1.f;
  float sg[5] = {1.f, 1.f, 1.f, 1.f, 1.f};
  float phi = h[0] + h[1] + h[2] + h[3] + h[4] + S5 * h[5] + S6 * h[6] +
              S7 * h[7] + z[0] + z[1] + z[2] + z[3] + S5 * z[4] +
              S5 * S6 * z[5] + S6 * S7 * z[6];
  _Float16* dst = Ach + (size_t)kb * 16384;
  const int halfoff = (2 * s) ^ (oct << 3);

  auto emit = [&](int g, float ph) {
    float r = ph * 0.07957747154594767f;  // ph/(4*pi) revolutions
    r = r - floorf(r);
    float sv = __builtin_amdgcn_sinf(r);
    float cv = __builtin_amdgcn_cosf(r);
    *(unsigned int*)(dst + (size_t)(g * 8 + oct) * 64 + halfoff) =
        packhalf2(cv, sv);
  };

  emit(0, phi);
#pragma unroll
  for (int jj = 1; jj < 32; ++jj) {
    const int b = __builtin_ctz(jj);
    const int w = 4 - b;
    float nbl = (w == 0) ? 0.f : sg[w - 1] * z[w - 1];
    float nbr = (w == 4) ? S5 * z[4] : sg[w + 1] * z[w];
    phi -= 2.f * sg[w] * (h[w] + nbl + nbr);
    sg[w] = -sg[w];
    emit(jj ^ (jj >> 1), phi);
  }
}

// ---------------------------------------------------------------------------
// K3: unified triangular split-K MFMA GEMM -> per-slab partial tiles.
// ---------------------------------------------------------------------------
#define ZSLABS 256

__global__ __launch_bounds__(256) void k_gemm(const _Float16* __restrict__ A,
                                              float* __restrict__ P,
                                              int kbPer) {
  __shared__ _Float16 lds[2][2][128][64];
  int bx = blockIdx.x, z = blockIdx.y;
  bool diag = (bx < 2);
  int mbase = (bx == 2) ? 0 : bx * 128;
  int nbase = (bx == 0) ? 0 : 128;
  int tile = (bx == 2) ? 1 : bx * 2;
  int bp = diag ? 0 : 1;
  int t = threadIdx.x, wave = t >> 6, lane = t & 63;
  int wm = wave >> 1, wn = wave & 1;
  unsigned int reMask = (z < ZSLABS / 2) ? 0u : 0x80008000u;
  unsigned int imMask = (z < ZSLABS / 2) ? 0x80000000u : 0x00008000u;
  int kb0 = z * kbPer;

  auto stage = [&](int it, int buf) {
    size_t kb = (size_t)(kb0 + it);
    const char* gA = (const char*)A + kb * 32768 + (size_t)mbase * 128;
    char* lA = (char*)&lds[buf][0][0][0];
#pragma unroll
    for (int q = 0; q < 4; q++) {
      int woff = wave * 4096 + q * 1024;
      load16_lds(gA + woff + lane * 16, lA + woff);
    }
    if (!diag) {
      const char* gB = (const char*)A + kb * 32768 + (size_t)nbase * 128;
      char* lB = (char*)&lds[buf][1][0][0];
#pragma unroll
      for (int q = 0; q < 4; q++) {
        int woff = wave * 4096 + q * 1024;
        load16_lds(gB + woff + lane * 16, lB + woff);
      }
    }
  };

  f32x4 accR[4][4] = {};
  f32x4 accI[4][4] = {};
  stage(0, 0);
  for (int it = 0; it < kbPer; ++it) {
    __syncthreads();
    if (it + 1 < kbPer) stage(it + 1, (it + 1) & 1);
    int buf = it & 1;
#pragma unroll
    for (int kk = 0; kk < 2; kk++) {
      int cbase = kk * 4 + (lane >> 4);
      half8 af[4], bfr[4], bfi[4];
#pragma unroll
      for (int fm = 0; fm < 4; fm++) {
        int r = wm * 64 + fm * 16 + (lane & 15);
        af[fm] = *(const half8*)&lds[buf][0][r][(cbase ^ (r & 7)) << 3];
      }
#pragma unroll
      for (int fn = 0; fn < 4; fn++) {
        int r = wn * 64 + fn * 16 + (lane & 15);
        half8 bv = *(const half8*)&lds[buf][bp][r][(cbase ^ (r & 7)) << 3];
        U4 u = __builtin_bit_cast(U4, bv), ur, ui;
#pragma unroll
        for (int q = 0; q < 4; q++) {
          unsigned int xv = u.w[q];
          ur.w[q] = xv ^ reMask;
          ui.w[q] = ((xv << 16) | (xv >> 16)) ^ imMask;
        }
        bfr[fn] = __builtin_bit_cast(half8, ur);
        bfi[fn] = __builtin_bit_cast(half8, ui);
      }
#pragma unroll
      for (int fm = 0; fm < 4; fm++)
#pragma unroll
        for (int fn = 0; fn < 4; fn++) {
          accR[fm][fn] = __builtin_amdgcn_mfma_f32_16x16x32_f16(
              af[fm], bfr[fn], accR[fm][fn], 0, 0, 0);
          accI[fm][fn] = __builtin_amdgcn_mfma_f32_16x16x32_f16(
              af[fm], bfi[fn], accI[fm][fn], 0, 0, 0);
        }
    }
  }
  float* PR = P + ((size_t)(tile * ZSLABS + z) * 2) * 16384;
  float* PI = PR + 16384;
  int r4 = (lane >> 4) * 4, cj = lane & 15;
#pragma unroll
  for (int fm = 0; fm < 4; fm++)
#pragma unroll
    for (int fn = 0; fn < 4; fn++)
#pragma unroll
      for (int r = 0; r < 4; r++) {
        int li = wm * 64 + fm * 16 + r4 + r;
        int lj = wn * 64 + fn * 16 + cj;
        PR[li * 128 + lj] = accR[fm][fn][r];
        PI[li * 128 + lj] = accI[fm][fn][r];
      }
}

// ---------------------------------------------------------------------------
// K4a/K4b: two-stage reduce -> Hermitian A + ||A||_F^2.
// ---------------------------------------------------------------------------
__global__ __launch_bounds__(128) void k_reduce1(const float* __restrict__ P,
                                                 float* __restrict__ Q) {
  int r = blockIdx.x, tile = blockIdx.y, g = blockIdx.z, c = threadIdx.x;
  const float* base =
      P + ((size_t)(tile * ZSLABS + g * 32) * 2) * 16384 + r * 128 + c;
  float vR = 0.f, vI = 0.f;
  for (int u = 0; u < 32; u++) {
    vR += base[(size_t)u * 32768];
    vI += base[(size_t)u * 32768 + 16384];
  }
  size_t qidx = ((size_t)(g * 3 + tile) * 128 + r) * 128 + c;
  Q[qidx] = vR;
  Q[qidx + (size_t)8 * 3 * 16384] = vI;
}

__global__ __launch_bounds__(128) void k_reduce2(const float* __restrict__ Q,
                                                 float* __restrict__ AR,
                                                 float* __restrict__ AI,
                                                 float* __restrict__ sumsq,
                                                 float scale) {
  int r = blockIdx.x, tile = blockIdx.y, c = threadIdx.x;
  float vR = 0.f, vI = 0.f;
#pragma unroll
  for (int g = 0; g < 8; g++) {
    size_t qidx = ((size_t)(g * 3 + tile) * 128 + r) * 128 + c;
    vR += Q[qidx];
    vI += Q[qidx + (size_t)8 * 3 * 16384];
  }
  vR *= scale;
  vI *= scale;
  int i = (tile == 2) ? 128 + r : r;
  int j = (tile == 0) ? c : 128 + c;
  float ss = 0.f;
  bool diagTile = (tile != 1);
  if (!diagTile || c > r) {
    AR[i * 256 + j] = vR;
    AR[j * 256 + i] = vR;
    AI[i * 256 + j] = vI;
    AI[j * 256 + i] = -vI;
    ss = 2.f * (vR * vR + vI * vI);
  } else if (c == r) {
    AR[i * 256 + j] = vR;
    AI[i * 256 + j] = 0.f;
    ss = vR * vR;
  }
#pragma unroll
  for (int o = 32; o > 0; o >>= 1) ss += __shfl_down(ss, o);
  __shared__ float w2[2];
  if ((c & 63) == 0) w2[c >> 6] = ss;
  __syncthreads();
  if (c == 0) atomicAdd(sumsq, w2[0] + w2[1]);
}

// ---------------------------------------------------------------------------
// K5: cooperative Newton-Schulz mega-kernel. 256 blocks x 1024 threads
// (1 block/CU, 4 waves/SIMD). Replaces 22 serial dispatches with grid.sync.
// Per iteration: phase1 Y = cur@cur (+||A^2||_F^2 on it 0) | sync |
// phase2 nxt = aC*cur - bC*(cur@Y) (final iter: trace vs A) | sync.
// Matmul structure identical to R9's k-split-4 kernels (proven).
// ---------------------------------------------------------------------------
__global__ __launch_bounds__(1024) void k_ns(
    const float* AR, const float* AI, float* XR, float* XI, float* YR,
    float* YI, float* ZR, float* ZI, float* scalars, float* out, int NIT) {
  cg::grid_group grid = cg::this_grid();
  __shared__ float rp[16][256][2];
  __shared__ float cpT[16][258][2];
  __shared__ float pacc[3][256][2];
  __shared__ float w16[16];
  const int t = threadIdx.x;
  const int bi = blockIdx.x >> 4, bj = blockIdx.x & 15;
  const int sub = t >> 8, tt = t & 255, ty = tt >> 4, tx = tt & 15;
  const int idx = (bi * 16 + ty) * 256 + bj * 16 + tx;

  // full-block complex 16x16-tile matmul: s = sum_k L[bi16+ty][k]*R[k][bj16+tx]
  // valid in (sR,sI) for sub==0 threads only. Also leaves L-rows in rp.
  auto MM = [&](const float* LRr, const float* LIi, const float* RRr,
                const float* RIi, float& sR, float& sI) {
    __syncthreads();  // protect LDS reuse
    {
      int r = t >> 6, c = (t & 63) * 4;
      const float4 vr = *(const float4*)&LRr[(bi * 16 + r) * 256 + c];
      const float4 vi = *(const float4*)&LIi[(bi * 16 + r) * 256 + c];
      rp[r][c + 0][0] = vr.x; rp[r][c + 1][0] = vr.y;
      rp[r][c + 2][0] = vr.z; rp[r][c + 3][0] = vr.w;
      rp[r][c + 0][1] = vi.x; rp[r][c + 1][1] = vi.y;
      rp[r][c + 2][1] = vi.z; rp[r][c + 3][1] = vi.w;
      int row = t >> 2, c0 = (t & 3) * 4;
      const float4 wr = *(const float4*)&RRr[row * 256 + bj * 16 + c0];
      const float4 wi = *(const float4*)&RIi[row * 256 + bj * 16 + c0];
      cpT[c0 + 0][row][0] = wr.x; cpT[c0 + 1][row][0] = wr.y;
      cpT[c0 + 2][row][0] = wr.z; cpT[c0 + 3][row][0] = wr.w;
      cpT[c0 + 0][row][1] = wi.x; cpT[c0 + 1][row][1] = wi.y;
      cpT[c0 + 2][row][1] = wi.z; cpT[c0 + 3][row][1] = wi.w;
    }
    __syncthreads();
    sR = 0.f;
    sI = 0.f;
    int k0 = sub * 64;
#pragma unroll 8
    for (int k = k0; k < k0 + 64; k++) {
      float xr = rp[ty][k][0], xi = rp[ty][k][1];
      float yr = cpT[tx][k][0], yi = cpT[tx][k][1];
      sR = fmaf(xr, yr, sR);
      sR = fmaf(-xi, yi, sR);
      sI = fmaf(xr, yi, sI);
      sI = fmaf(xi, yr, sI);
    }
    if (sub) {
      pacc[sub - 1][tt][0] = sR;
      pacc[sub - 1][tt][1] = sI;
    }
    __syncthreads();
    if (sub == 0) {
      sR += (pacc[0][tt][0] + pacc[1][tt][0]) + pacc[2][tt][0];
      sI += (pacc[0][tt][1] + pacc[1][tt][1]) + pacc[2][tt][1];
    }
  };

  // block-wide reduce-add of v into *dst (scaled); uniform call sites only.
  auto blockAtomic = [&](float v, float* dst, float scale) {
#pragma unroll
    for (int o = 32; o > 0; o >>= 1) v += __shfl_down(v, o);
    if ((t & 63) == 0) w16[t >> 6] = v;
    __syncthreads();
    if (t == 0) {
      float s = 0.f;
#pragma unroll
      for (int q = 0; q < 16; q++) s += w16[q];
      atomicAdd(dst, scale * s);
    }
  };

  const float *cR = AR, *cI = AI;
  float *nR = XR, *nI = XI;
  for (int it = 0; it < NIT; ++it) {
    // -------- phase 1: Y = cur @ cur --------
    float sR, sI;
    MM(cR, cI, cR, cI, sR, sI);
    if (sub == 0) {
      YR[idx] = sR;
      YI[idx] = sI;
    }
    if (it == 0) {
      float v = (sub == 0) ? (sR * sR + sI * sI) : 0.f;
      blockAtomic(v, scalars + 1, 1.0f);
    }
    grid.sync();
    // -------- phase 2: nxt = aC*cur - bC*(cur @ Y) --------
    float mR, mI;
    MM(cR, cI, YR, YI, mR, mI);
    float aC, bC;
    int mode = (it == 0) ? 0 : (it <= 6 ? 1 : 2);
    if (mode == 0) {
      float f2 = scalars[0];
      float f = sqrtf(f2);
      float Rhat = 1.41421356f * sqrtf(scalars[1]) / f2;
      float g = 1.0f / (1.75f * Rhat);
      aC = 1.5f * g / f;
      float gf = g / f;
      bC = 0.5f * gf * gf * gf;
    } else if (mode == 1) {
      aC = 2.0f;
      bC = 1.0f;
    } else {
      aC = 1.5f;
      bC = 0.5f;
    }
    if (it < NIT - 1) {
      if (sub == 0) {
        // cur[idx] is staged: rp[ty][bj*16+tx]
        nR[idx] = aC * rp[ty][bj * 16 + tx][0] - bC * mR;
        nI[idx] = aC * rp[ty][bj * 16 + tx][1] - bC * mI;
      }
      grid.sync();
    } else {
      float v = 0.f;
      if (sub == 0) {
        float zr = aC * rp[ty][bj * 16 + tx][0] - bC * mR;
        float zi = aC * rp[ty][bj * 16 + tx][1] - bC * mI;
        v = AR[idx] * zr + AI[idx] * zi;
      }
      blockAtomic(v, out, -0.5f);
    }
    if (it == 0) {
      cR = XR; cI = XI; nR = ZR; nI = ZI;
    } else {
      const float* tmpR = cR; const float* tmpI = cI;
      cR = nR; cI = nI;
      nR = (float*)tmpR; nI = (float*)tmpI;
    }
  }
}

// ---------------------------------------------------------------------------
extern "C" void kernel_launch(void* const* d_in, const int* in_sizes, int n_in,
                              void* d_out, int out_size, void* d_ws,
                              size_t ws_size, hipStream_t stream) {
  const float* x1 = (const float*)d_in[0];
  const float* x0 = (const float*)d_in[1];
  const float* W1 = (const float*)d_in[2];
  const float* b1 = (const float*)d_in[3];
  const float* W2 = (const float*)d_in[4];
  const float* b2 = (const float*)d_in[5];
  const float* W3 = (const float*)d_in[6];
  const float* b3 = (const float*)d_in[7];
  (void)n_in;
  (void)out_size;
  (void)ws_size;

  const int B = in_sizes[0] / 8;       // 65536
  const int total = 2 * B;             // 131072
  const int totalKb = total / 32;      // 4096
  const int kbPer = totalKb / ZSLABS;  // 16

  char* ws = (char*)d_ws;
  size_t off = 0;
  auto carve = [&](size_t bytes) -> void* {
    off = (off + 255) & ~(size_t)255;
    void* p = ws + off;
    off += bytes;
    return p;
  };
  float* hz = (float*)carve((size_t)total * 16 * 4);              // 8.4 MB
  _Float16* Ach = (_Float16*)carve((size_t)totalKb * 16384 * 2);  // 134 MB
  float* P = (float*)carve((size_t)3 * ZSLABS * 2 * 16384 * 4);   // 100.7 MB
  float* Q = (float*)carve((size_t)2 * 8 * 3 * 16384 * 4);        // 3.1 MB
  float* scalars = (float*)carve(256);  // [0]=sumsq(A), [1]=sumsq(A^2)
  float* AR = (float*)carve(256 * 256 * 4);
  float* AI = (float*)carve(256 * 256 * 4);
  float* XR = (float*)carve(256 * 256 * 4);
  float* XI = (float*)carve(256 * 256 * 4);
  float* YR = (float*)carve(256 * 256 * 4);
  float* YI = (float*)carve(256 * 256 * 4);
  float* ZR = (float*)carve(256 * 256 * 4);
  float* ZI = (float*)carve(256 * 256 * 4);

  k_mlp<<<(total + 255) / 256, 256, 0, stream>>>(
      x1, x0, W1, b1, W2, b2, W3, b3, hz, B, scalars, (float*)d_out);
  k_gen<<<totalKb, 256, 0, stream>>>(hz, Ach);
  k_gemm<<<dim3(3, ZSLABS), 256, 0, stream>>>(Ach, P, kbPer);
  k_reduce1<<<dim3(128, 3, 8), 128, 0, stream>>>(P, Q);
  k_reduce2<<<dim3(128, 3), 128, 0, stream>>>(Q, AR, AI, scalars,
                                              1.0f / (256.0f * (float)B));

  // NS schedule (R9-calibrated, absmax 1.22e-4 vs 3.32e-4 threshold):
  // 1x clamp(1.5-NS, rescaled, raw-A norm-folded) + 6x (2x - x^3)
  // + 4x (1.5-NS); trace fused. Single cooperative dispatch.
  int nit = 11;
  float* outp = (float*)d_out;
  void* args[] = {&AR, &AI, &XR, &XI, &YR, &YI,
                  &ZR, &ZI, &scalars, &outp, &nit};
  hipLaunchCooperativeKernel((void*)k_ns, dim3(256), dim3(1024), args, 0,
                             stream);
}

// Round 11
// 616.089 us; speedup vs baseline: 1.4554x; 1.4554x over previous
//
#include <hip/hip_runtime.h>
#include <cstdint>
#include <cstddef>
#include <utility>

#define PI_F 3.14159265358979323846f

typedef __attribute__((ext_vector_type(8))) _Float16 half8;
typedef __attribute__((ext_vector_type(4))) float f32x4;

struct U4 { unsigned int w[4]; };

static __device__ __forceinline__ unsigned int packhalf2(float c, float s) {
  _Float16 hc = (_Float16)c, hs = (_Float16)s;
  unsigned short uc = __builtin_bit_cast(unsigned short, hc);
  unsigned short us = __builtin_bit_cast(unsigned short, hs);
  return (unsigned int)uc | ((unsigned int)us << 16);
}

static __device__ __forceinline__ void load16_lds(const void* g, void* l) {
  __builtin_amdgcn_global_load_lds(
      (const __attribute__((address_space(1))) unsigned int*)g,
      (__attribute__((address_space(3))) unsigned int*)l, 16, 0, 0);
}

// ---------------------------------------------------------------------------
// Hand-rolled grid barrier, AGENT (device) scope. One fresh counter per
// barrier instance (zeroed each launch) -> no sense-reversal/reset hazard.
// release: __threadfence (L2 wb) before arrival; acquire: __threadfence
// (inv) after the count completes. cg::grid.sync measured ~34 us on gfx950
// (R10); this targets ~2-4 us.
// ---------------------------------------------------------------------------
static __device__ __forceinline__ void gridbar(unsigned int* ctr,
                                               unsigned int nb) {
  __syncthreads();
  if (threadIdx.x == 0) {
    __threadfence();  // release: make prior stores device-visible
    __hip_atomic_fetch_add(ctr, 1u, __ATOMIC_RELAXED,
                           __HIP_MEMORY_SCOPE_AGENT);
    while (__hip_atomic_load(ctr, __ATOMIC_RELAXED,
                             __HIP_MEMORY_SCOPE_AGENT) < nb) {
      __builtin_amdgcn_s_sleep(1);
    }
    __threadfence();  // acquire: invalidate stale cached lines
  }
  __syncthreads();
}

// ---------------------------------------------------------------------------
// K1: MLP for all 2B samples -> hz[sample][16] = {h[0..7], z[0..6], 0}.
// Block 0 thread 0 also zero-inits scalars + out.
// ---------------------------------------------------------------------------
__global__ __launch_bounds__(256) void k_mlp(
    const float* __restrict__ x1, const float* __restrict__ x0,
    const float* __restrict__ W1, const float* __restrict__ b1,
    const float* __restrict__ W2, const float* __restrict__ b2,
    const float* __restrict__ W3, const float* __restrict__ b3,
    float* __restrict__ hz, int B, float* __restrict__ scalars,
    float* __restrict__ out) {
  int s = blockIdx.x * blockDim.x + threadIdx.x;
  if (blockIdx.x == 0 && threadIdx.x == 0) {
    scalars[0] = 0.f;
    scalars[1] = 0.f;
    out[0] = 0.f;
  }
  if (s >= 2 * B) return;
  const float* xp = (s < B) ? (x1 + (size_t)s * 8) : (x0 + (size_t)(s - B) * 8);
  float x[8];
#pragma unroll
  for (int k = 0; k < 8; k++) x[k] = xp[k];
  float a1[10];
#pragma unroll
  for (int o = 0; o < 10; o++) {
    float v = b1[o];
#pragma unroll
    for (int k = 0; k < 8; k++) v = fmaf(W1[o * 8 + k], x[k], v);
    a1[o] = fmaxf(v, 0.f);
  }
  float a2[10];
#pragma unroll
  for (int o = 0; o < 10; o++) {
    float v = b2[o];
#pragma unroll
    for (int k = 0; k < 10; k++) v = fmaf(W2[o * 10 + k], a1[k], v);
    a2[o] = fmaxf(v, 0.f);
  }
  float h[8];
#pragma unroll
  for (int o = 0; o < 8; o++) {
    float v = b3[o];
#pragma unroll
    for (int k = 0; k < 10; k++) v = fmaf(W3[o * 10 + k], a2[k], v);
    h[o] = v;
  }
  float outv[16];
#pragma unroll
  for (int k = 0; k < 8; k++) outv[k] = h[k];
#pragma unroll
  for (int k = 0; k < 7; k++) outv[8 + k] = (PI_F - h[k]) * (PI_F - h[k + 1]);
  outv[15] = 0.f;
  float4* dst = (float4*)(hz + (size_t)s * 16);
#pragma unroll
  for (int q = 0; q < 4; q++) dst[q] = ((float4*)outv)[q];
}

// ---------------------------------------------------------------------------
// K2: generate fp16 (cos,sin) pairs. A layout: [kb][256 rows][64 halfs],
// 16B chunks XOR-swizzled by (row&7). Gray-code walk + HW v_sin/v_cos.
// ---------------------------------------------------------------------------
__global__ __launch_bounds__(256) void k_gen(const float* __restrict__ hz,
                                             _Float16* __restrict__ Ach) {
  __shared__ float hzl[32][17];
  int kb = blockIdx.x, t = threadIdx.x;
  if (t < 128) {
    int smp = t >> 2, q = t & 3;
    const float4 v =
        *(const float4*)(hz + (size_t)(kb * 32 + smp) * 16 + q * 4);
    hzl[smp][q * 4 + 0] = v.x;
    hzl[smp][q * 4 + 1] = v.y;
    hzl[smp][q * 4 + 2] = v.z;
    hzl[smp][q * 4 + 3] = v.w;
  }
  __syncthreads();
  int s = t & 31, oct = t >> 5;
  float h[8], z[7];
#pragma unroll
  for (int k = 0; k < 8; k++) h[k] = hzl[s][k];
#pragma unroll
  for (int k = 0; k < 7; k++) z[k] = hzl[s][8 + k];
  float S5 = (oct & 4) ? -1.f : 1.f;
  float S6 = (oct & 2) ? -1.f : 1.f;
  float S7 = (oct & 1) ? -1.f : 1.f;
  float sg[5] = {1.f, 1.f, 1.f, 1.f, 1.f};
  float phi = h[0] + h[1] + h[2] + h[3] + h[4] + S5 * h[5] + S6 * h[6] +
              S7 * h[7] + z[0] + z[1] + z[2] + z[3] + S5 * z[4] +
              S5 * S6 * z[5] + S6 * S7 * z[6];
  _Float16* dst = Ach + (size_t)kb * 16384;
  const int halfoff = (2 * s) ^ (oct << 3);

  auto emit = [&](int g, float ph) {
    float r = ph * 0.07957747154594767f;  // ph/(4*pi) revolutions
    r = r - floorf(r);
    float sv = __builtin_amdgcn_sinf(r);
    float cv = __builtin_amdgcn_cosf(r);
    *(unsigned int*)(dst + (size_t)(g * 8 + oct) * 64 + halfoff) =
        packhalf2(cv, sv);
  };

  emit(0, phi);
#pragma unroll
  for (int jj = 1; jj < 32; ++jj) {
    const int b = __builtin_ctz(jj);
    const int w = 4 - b;
    float nbl = (w == 0) ? 0.f : sg[w - 1] * z[w - 1];
    float nbr = (w == 4) ? S5 * z[4] : sg[w + 1] * z[w];
    phi -= 2.f * sg[w] * (h[w] + nbl + nbr);
    sg[w] = -sg[w];
    emit(jj ^ (jj >> 1), phi);
  }
}

// ---------------------------------------------------------------------------
// K3: unified triangular split-K MFMA GEMM -> per-slab partial tiles.
// ---------------------------------------------------------------------------
#define ZSLABS 256

__global__ __launch_bounds__(256) void k_gemm(const _Float16* __restrict__ A,
                                              float* __restrict__ P,
                                              int kbPer) {
  __shared__ _Float16 lds[2][2][128][64];
  int bx = blockIdx.x, z = blockIdx.y;
  bool diag = (bx < 2);
  int mbase = (bx == 2) ? 0 : bx * 128;
  int nbase = (bx == 0) ? 0 : 128;
  int tile = (bx == 2) ? 1 : bx * 2;
  int bp = diag ? 0 : 1;
  int t = threadIdx.x, wave = t >> 6, lane = t & 63;
  int wm = wave >> 1, wn = wave & 1;
  unsigned int reMask = (z < ZSLABS / 2) ? 0u : 0x80008000u;
  unsigned int imMask = (z < ZSLABS / 2) ? 0x80000000u : 0x00008000u;
  int kb0 = z * kbPer;

  auto stage = [&](int it, int buf) {
    size_t kb = (size_t)(kb0 + it);
    const char* gA = (const char*)A + kb * 32768 + (size_t)mbase * 128;
    char* lA = (char*)&lds[buf][0][0][0];
#pragma unroll
    for (int q = 0; q < 4; q++) {
      int woff = wave * 4096 + q * 1024;
      load16_lds(gA + woff + lane * 16, lA + woff);
    }
    if (!diag) {
      const char* gB = (const char*)A + kb * 32768 + (size_t)nbase * 128;
      char* lB = (char*)&lds[buf][1][0][0];
#pragma unroll
      for (int q = 0; q < 4; q++) {
        int woff = wave * 4096 + q * 1024;
        load16_lds(gB + woff + lane * 16, lB + woff);
      }
    }
  };

  f32x4 accR[4][4] = {};
  f32x4 accI[4][4] = {};
  stage(0, 0);
  for (int it = 0; it < kbPer; ++it) {
    __syncthreads();
    if (it + 1 < kbPer) stage(it + 1, (it + 1) & 1);
    int buf = it & 1;
#pragma unroll
    for (int kk = 0; kk < 2; kk++) {
      int cbase = kk * 4 + (lane >> 4);
      half8 af[4], bfr[4], bfi[4];
#pragma unroll
      for (int fm = 0; fm < 4; fm++) {
        int r = wm * 64 + fm * 16 + (lane & 15);
        af[fm] = *(const half8*)&lds[buf][0][r][(cbase ^ (r & 7)) << 3];
      }
#pragma unroll
      for (int fn = 0; fn < 4; fn++) {
        int r = wn * 64 + fn * 16 + (lane & 15);
        half8 bv = *(const half8*)&lds[buf][bp][r][(cbase ^ (r & 7)) << 3];
        U4 u = __builtin_bit_cast(U4, bv), ur, ui;
#pragma unroll
        for (int q = 0; q < 4; q++) {
          unsigned int xv = u.w[q];
          ur.w[q] = xv ^ reMask;
          ui.w[q] = ((xv << 16) | (xv >> 16)) ^ imMask;
        }
        bfr[fn] = __builtin_bit_cast(half8, ur);
        bfi[fn] = __builtin_bit_cast(half8, ui);
      }
#pragma unroll
      for (int fm = 0; fm < 4; fm++)
#pragma unroll
        for (int fn = 0; fn < 4; fn++) {
          accR[fm][fn] = __builtin_amdgcn_mfma_f32_16x16x32_f16(
              af[fm], bfr[fn], accR[fm][fn], 0, 0, 0);
          accI[fm][fn] = __builtin_amdgcn_mfma_f32_16x16x32_f16(
              af[fm], bfi[fn], accI[fm][fn], 0, 0, 0);
        }
    }
  }
  float* PR = P + ((size_t)(tile * ZSLABS + z) * 2) * 16384;
  float* PI = PR + 16384;
  int r4 = (lane >> 4) * 4, cj = lane & 15;
#pragma unroll
  for (int fm = 0; fm < 4; fm++)
#pragma unroll
    for (int fn = 0; fn < 4; fn++)
#pragma unroll
      for (int r = 0; r < 4; r++) {
        int li = wm * 64 + fm * 16 + r4 + r;
        int lj = wn * 64 + fn * 16 + cj;
        PR[li * 128 + lj] = accR[fm][fn][r];
        PI[li * 128 + lj] = accI[fm][fn][r];
      }
}

// ---------------------------------------------------------------------------
// K4a/K4b: two-stage reduce -> Hermitian A + ||A||_F^2.
// ---------------------------------------------------------------------------
__global__ __launch_bounds__(128) void k_reduce1(const float* __restrict__ P,
                                                 float* __restrict__ Q) {
  int r = blockIdx.x, tile = blockIdx.y, g = blockIdx.z, c = threadIdx.x;
  const float* base =
      P + ((size_t)(tile * ZSLABS + g * 32) * 2) * 16384 + r * 128 + c;
  float vR = 0.f, vI = 0.f;
  for (int u = 0; u < 32; u++) {
    vR += base[(size_t)u * 32768];
    vI += base[(size_t)u * 32768 + 16384];
  }
  size_t qidx = ((size_t)(g * 3 + tile) * 128 + r) * 128 + c;
  Q[qidx] = vR;
  Q[qidx + (size_t)8 * 3 * 16384] = vI;
}

__global__ __launch_bounds__(128) void k_reduce2(const float* __restrict__ Q,
                                                 float* __restrict__ AR,
                                                 float* __restrict__ AI,
                                                 float* __restrict__ sumsq,
                                                 float scale) {
  int r = blockIdx.x, tile = blockIdx.y, c = threadIdx.x;
  float vR = 0.f, vI = 0.f;
#pragma unroll
  for (int g = 0; g < 8; g++) {
    size_t qidx = ((size_t)(g * 3 + tile) * 128 + r) * 128 + c;
    vR += Q[qidx];
    vI += Q[qidx + (size_t)8 * 3 * 16384];
  }
  vR *= scale;
  vI *= scale;
  int i = (tile == 2) ? 128 + r : r;
  int j = (tile == 0) ? c : 128 + c;
  float ss = 0.f;
  bool diagTile = (tile != 1);
  if (!diagTile || c > r) {
    AR[i * 256 + j] = vR;
    AR[j * 256 + i] = vR;
    AI[i * 256 + j] = vI;
    AI[j * 256 + i] = -vI;
    ss = 2.f * (vR * vR + vI * vI);
  } else if (c == r) {
    AR[i * 256 + j] = vR;
    AI[i * 256 + j] = 0.f;
    ss = vR * vR;
  }
#pragma unroll
  for (int o = 32; o > 0; o >>= 1) ss += __shfl_down(ss, o);
  __shared__ float w2[2];
  if ((c & 63) == 0) w2[c >> 6] = ss;
  __syncthreads();
  if (c == 0) atomicAdd(sumsq, w2[0] + w2[1]);
}

// ---------------------------------------------------------------------------
// K5: cooperative Newton-Schulz mega-kernel with HAND-ROLLED agent-scope
// barriers (cg::grid.sync measured ~34 us/sync in R10 -> 787 us; this
// targets ~2-4 us/barrier). 256 blocks x 1024 threads, 1 block/CU.
// rp padded to [16][258][2]: the [16][256][2] stride made every rp[ty][k]
// read a 4-way bank conflict (R10: SQ_LDS_BANK_CONFLICT=1.44e7).
// ---------------------------------------------------------------------------
__global__ __launch_bounds__(1024) void k_ns(
    const float* AR, const float* AI, float* XR, float* XI, float* YR,
    float* YI, float* ZR, float* ZI, float* scalars, float* out,
    unsigned int* bar, int NIT) {
  __shared__ float rp[16][258][2];
  __shared__ float cpT[16][258][2];
  __shared__ float pacc[3][256][2];
  __shared__ float w16[16];
  const int t = threadIdx.x;
  const int bi = blockIdx.x >> 4, bj = blockIdx.x & 15;
  const int sub = t >> 8, tt = t & 255, ty = tt >> 4, tx = tt & 15;
  const int idx = (bi * 16 + ty) * 256 + bj * 16 + tx;
  const unsigned int NB = gridDim.x;
  int barIdx = 0;

  // full-block complex 16x16-tile matmul: s = sum_k L[bi16+ty][k]*R[k][bj16+tx]
  // valid in (sR,sI) for sub==0 threads only. Leaves L-rows staged in rp.
  auto MM = [&](const float* LRr, const float* LIi, const float* RRr,
                const float* RIi, float& sR, float& sI) {
    __syncthreads();  // protect LDS reuse
    {
      int r = t >> 6, c = (t & 63) * 4;
      const float4 vr = *(const float4*)&LRr[(bi * 16 + r) * 256 + c];
      const float4 vi = *(const float4*)&LIi[(bi * 16 + r) * 256 + c];
      float4 p0 = {vr.x, vi.x, vr.y, vi.y};
      float4 p1 = {vr.z, vi.z, vr.w, vi.w};
      *(float4*)&rp[r][c][0] = p0;
      *(float4*)&rp[r][c + 2][0] = p1;
      int row = t >> 2, c0 = (t & 3) * 4;
      const float4 wr = *(const float4*)&RRr[row * 256 + bj * 16 + c0];
      const float4 wi = *(const float4*)&RIi[row * 256 + bj * 16 + c0];
      float2 q0 = {wr.x, wi.x}, q1 = {wr.y, wi.y};
      float2 q2 = {wr.z, wi.z}, q3 = {wr.w, wi.w};
      *(float2*)&cpT[c0 + 0][row][0] = q0;
      *(float2*)&cpT[c0 + 1][row][0] = q1;
      *(float2*)&cpT[c0 + 2][row][0] = q2;
      *(float2*)&cpT[c0 + 3][row][0] = q3;
    }
    __syncthreads();
    sR = 0.f;
    sI = 0.f;
    int k0 = sub * 64;
#pragma unroll 8
    for (int k = k0; k < k0 + 64; k++) {
      float xr = rp[ty][k][0], xi = rp[ty][k][1];
      float yr = cpT[tx][k][0], yi = cpT[tx][k][1];
      sR = fmaf(xr, yr, sR);
      sR = fmaf(-xi, yi, sR);
      sI = fmaf(xr, yi, sI);
      sI = fmaf(xi, yr, sI);
    }
    if (sub) {
      pacc[sub - 1][tt][0] = sR;
      pacc[sub - 1][tt][1] = sI;
    }
    __syncthreads();
    if (sub == 0) {
      sR += (pacc[0][tt][0] + pacc[1][tt][0]) + pacc[2][tt][0];
      sI += (pacc[0][tt][1] + pacc[1][tt][1]) + pacc[2][tt][1];
    }
  };

  auto blockAtomic = [&](float v, float* dst, float scale) {
#pragma unroll
    for (int o = 32; o > 0; o >>= 1) v += __shfl_down(v, o);
    if ((t & 63) == 0) w16[t >> 6] = v;
    __syncthreads();
    if (t == 0) {
      float s = 0.f;
#pragma unroll
      for (int q = 0; q < 16; q++) s += w16[q];
      atomicAdd(dst, scale * s);
    }
  };

  const float *cR = AR, *cI = AI;
  float *nR = XR, *nI = XI;
  for (int it = 0; it < NIT; ++it) {
    // -------- phase 1: Y = cur @ cur --------
    float sR, sI;
    MM(cR, cI, cR, cI, sR, sI);
    if (sub == 0) {
      YR[idx] = sR;
      YI[idx] = sI;
    }
    if (it == 0) {
      float v = (sub == 0) ? (sR * sR + sI * sI) : 0.f;
      blockAtomic(v, scalars + 1, 1.0f);
    }
    gridbar(&bar[barIdx++], NB);
    // -------- phase 2: nxt = aC*cur - bC*(cur @ Y) --------
    float mR, mI;
    MM(cR, cI, YR, YI, mR, mI);
    float aC, bC;
    int mode = (it == 0) ? 0 : (it <= 6 ? 1 : 2);
    if (mode == 0) {
      float f2 = scalars[0];
      float f = sqrtf(f2);
      float Rhat = 1.41421356f * sqrtf(scalars[1]) / f2;
      float g = 1.0f / (1.75f * Rhat);
      aC = 1.5f * g / f;
      float gf = g / f;
      bC = 0.5f * gf * gf * gf;
    } else if (mode == 1) {
      aC = 2.0f;
      bC = 1.0f;
    } else {
      aC = 1.5f;
      bC = 0.5f;
    }
    if (it < NIT - 1) {
      if (sub == 0) {
        nR[idx] = aC * rp[ty][bj * 16 + tx][0] - bC * mR;
        nI[idx] = aC * rp[ty][bj * 16 + tx][1] - bC * mI;
      }
      gridbar(&bar[barIdx++], NB);
    } else {
      float v = 0.f;
      if (sub == 0) {
        float zr = aC * rp[ty][bj * 16 + tx][0] - bC * mR;
        float zi = aC * rp[ty][bj * 16 + tx][1] - bC * mI;
        v = AR[idx] * zr + AI[idx] * zi;
      }
      blockAtomic(v, out, -0.5f);
    }
    if (it == 0) {
      cR = XR; cI = XI; nR = ZR; nI = ZI;
    } else {
      const float* tmpR = cR; const float* tmpI = cI;
      cR = nR; cI = nI;
      nR = (float*)tmpR; nI = (float*)tmpI;
    }
  }
}

// ---------------------------------------------------------------------------
extern "C" void kernel_launch(void* const* d_in, const int* in_sizes, int n_in,
                              void* d_out, int out_size, void* d_ws,
                              size_t ws_size, hipStream_t stream) {
  const float* x1 = (const float*)d_in[0];
  const float* x0 = (const float*)d_in[1];
  const float* W1 = (const float*)d_in[2];
  const float* b1 = (const float*)d_in[3];
  const float* W2 = (const float*)d_in[4];
  const float* b2 = (const float*)d_in[5];
  const float* W3 = (const float*)d_in[6];
  const float* b3 = (const float*)d_in[7];
  (void)n_in;
  (void)out_size;
  (void)ws_size;

  const int B = in_sizes[0] / 8;       // 65536
  const int total = 2 * B;             // 131072
  const int totalKb = total / 32;      // 4096
  const int kbPer = totalKb / ZSLABS;  // 16

  char* ws = (char*)d_ws;
  size_t off = 0;
  auto carve = [&](size_t bytes) -> void* {
    off = (off + 255) & ~(size_t)255;
    void* p = ws + off;
    off += bytes;
    return p;
  };
  float* hz = (float*)carve((size_t)total * 16 * 4);              // 8.4 MB
  _Float16* Ach = (_Float16*)carve((size_t)totalKb * 16384 * 2);  // 134 MB
  float* P = (float*)carve((size_t)3 * ZSLABS * 2 * 16384 * 4);   // 100.7 MB
  float* Q = (float*)carve((size_t)2 * 8 * 3 * 16384 * 4);        // 3.1 MB
  float* scalars = (float*)carve(256);
  unsigned int* bar = (unsigned int*)carve(256);  // 21 barrier counters
  float* AR = (float*)carve(256 * 256 * 4);
  float* AI = (float*)carve(256 * 256 * 4);
  float* XR = (float*)carve(256 * 256 * 4);
  float* XI = (float*)carve(256 * 256 * 4);
  float* YR = (float*)carve(256 * 256 * 4);
  float* YI = (float*)carve(256 * 256 * 4);
  float* ZR = (float*)carve(256 * 256 * 4);
  float* ZI = (float*)carve(256 * 256 * 4);

  hipMemsetAsync(bar, 0, 256, stream);

  k_mlp<<<(total + 255) / 256, 256, 0, stream>>>(
      x1, x0, W1, b1, W2, b2, W3, b3, hz, B, scalars, (float*)d_out);
  k_gen<<<totalKb, 256, 0, stream>>>(hz, Ach);
  k_gemm<<<dim3(3, ZSLABS), 256, 0, stream>>>(Ach, P, kbPer);
  k_reduce1<<<dim3(128, 3, 8), 128, 0, stream>>>(P, Q);
  k_reduce2<<<dim3(128, 3), 128, 0, stream>>>(Q, AR, AI, scalars,
                                              1.0f / (256.0f * (float)B));

  // NS schedule (R9-calibrated): 1x clamp(1.5-NS, rescaled, norm-folded)
  // + 6x (2x - x^3) + 4x (1.5-NS); trace fused. One cooperative dispatch,
  // hand-rolled barriers.
  int nit = 11;
  float* outp = (float*)d_out;
  void* args[] = {&AR, &AI, &XR, &XI, &YR,  &YI,
                  &ZR, &ZI, &scalars, &outp, &bar, &nit};
  hipLaunchCooperativeKernel((void*)k_ns, dim3(256), dim3(1024), args, 0,
                             stream);
}

// Round 12
// 252.992 us; speedup vs baseline: 3.5442x; 2.4352x over previous
//
#include <hip/hip_runtime.h>
#include <cstdint>
#include <cstddef>
#include <utility>

#define PI_F 3.14159265358979323846f

typedef __attribute__((ext_vector_type(8))) _Float16 half8;
typedef __attribute__((ext_vector_type(4))) float f32x4;

struct U4 { unsigned int w[4]; };

static __device__ __forceinline__ unsigned int packhalf2(float c, float s) {
  _Float16 hc = (_Float16)c, hs = (_Float16)s;
  unsigned short uc = __builtin_bit_cast(unsigned short, hc);
  unsigned short us = __builtin_bit_cast(unsigned short, hs);
  return (unsigned int)uc | ((unsigned int)us << 16);
}

static __device__ __forceinline__ void load16_lds(const void* g, void* l) {
  __builtin_amdgcn_global_load_lds(
      (const __attribute__((address_space(1))) unsigned int*)g,
      (__attribute__((address_space(3))) unsigned int*)l, 16, 0, 0);
}

// ---------------------------------------------------------------------------
// K1: MLP for all 2B samples -> hz[sample][16] = {h[0..7], z[0..6], 0}.
// Block 0 thread 0 also zero-inits scalars + out.
// ---------------------------------------------------------------------------
__global__ __launch_bounds__(256) void k_mlp(
    const float* __restrict__ x1, const float* __restrict__ x0,
    const float* __restrict__ W1, const float* __restrict__ b1,
    const float* __restrict__ W2, const float* __restrict__ b2,
    const float* __restrict__ W3, const float* __restrict__ b3,
    float* __restrict__ hz, int B, float* __restrict__ scalars,
    float* __restrict__ out) {
  int s = blockIdx.x * blockDim.x + threadIdx.x;
  if (blockIdx.x == 0 && threadIdx.x == 0) {
    scalars[0] = 0.f;
    scalars[1] = 0.f;
    out[0] = 0.f;
  }
  if (s >= 2 * B) return;
  const float* xp = (s < B) ? (x1 + (size_t)s * 8) : (x0 + (size_t)(s - B) * 8);
  float x[8];
#pragma unroll
  for (int k = 0; k < 8; k++) x[k] = xp[k];
  float a1[10];
#pragma unroll
  for (int o = 0; o < 10; o++) {
    float v = b1[o];
#pragma unroll
    for (int k = 0; k < 8; k++) v = fmaf(W1[o * 8 + k], x[k], v);
    a1[o] = fmaxf(v, 0.f);
  }
  float a2[10];
#pragma unroll
  for (int o = 0; o < 10; o++) {
    float v = b2[o];
#pragma unroll
    for (int k = 0; k < 10; k++) v = fmaf(W2[o * 10 + k], a1[k], v);
    a2[o] = fmaxf(v, 0.f);
  }
  float h[8];
#pragma unroll
  for (int o = 0; o < 8; o++) {
    float v = b3[o];
#pragma unroll
    for (int k = 0; k < 10; k++) v = fmaf(W3[o * 10 + k], a2[k], v);
    h[o] = v;
  }
  float outv[16];
#pragma unroll
  for (int k = 0; k < 8; k++) outv[k] = h[k];
#pragma unroll
  for (int k = 0; k < 7; k++) outv[8 + k] = (PI_F - h[k]) * (PI_F - h[k + 1]);
  outv[15] = 0.f;
  float4* dst = (float4*)(hz + (size_t)s * 16);
#pragma unroll
  for (int q = 0; q < 4; q++) dst[q] = ((float4*)outv)[q];
}

// ---------------------------------------------------------------------------
// K2: generate fp16 (cos,sin) pairs. A layout: [kb][256 rows][64 halfs],
// 16B chunks XOR-swizzled by (row&7). Gray-code walk + HW v_sin/v_cos.
// ---------------------------------------------------------------------------
__global__ __launch_bounds__(256) void k_gen(const float* __restrict__ hz,
                                             _Float16* __restrict__ Ach) {
  __shared__ float hzl[32][17];
  int kb = blockIdx.x, t = threadIdx.x;
  if (t < 128) {
    int smp = t >> 2, q = t & 3;
    const float4 v =
        *(const float4*)(hz + (size_t)(kb * 32 + smp) * 16 + q * 4);
    hzl[smp][q * 4 + 0] = v.x;
    hzl[smp][q * 4 + 1] = v.y;
    hzl[smp][q * 4 + 2] = v.z;
    hzl[smp][q * 4 + 3] = v.w;
  }
  __syncthreads();
  int s = t & 31, oct = t >> 5;
  float h[8], z[7];
#pragma unroll
  for (int k = 0; k < 8; k++) h[k] = hzl[s][k];
#pragma unroll
  for (int k = 0; k < 7; k++) z[k] = hzl[s][8 + k];
  float S5 = (oct & 4) ? -1.f : 1.f;
  float S6 = (oct & 2) ? -1.f : 1.f;
  float S7 = (oct & 1) ? -1.f : 1.f;
  float sg[5] = {1.f, 1.f, 1.f, 1.f, 1.f};
  float phi = h[0] + h[1] + h[2] + h[3] + h[4] + S5 * h[5] + S6 * h[6] +
              S7 * h[7] + z[0] + z[1] + z[2] + z[3] + S5 * z[4] +
              S5 * S6 * z[5] + S6 * S7 * z[6];
  _Float16* dst = Ach + (size_t)kb * 16384;
  const int halfoff = (2 * s) ^ (oct << 3);

  auto emit = [&](int g, float ph) {
    float r = ph * 0.07957747154594767f;  // ph/(4*pi) revolutions
    r = r - floorf(r);
    float sv = __builtin_amdgcn_sinf(r);
    float cv = __builtin_amdgcn_cosf(r);
    *(unsigned int*)(dst + (size_t)(g * 8 + oct) * 64 + halfoff) =
        packhalf2(cv, sv);
  };

  emit(0, phi);
#pragma unroll
  for (int jj = 1; jj < 32; ++jj) {
    const int b = __builtin_ctz(jj);
    const int w = 4 - b;
    float nbl = (w == 0) ? 0.f : sg[w - 1] * z[w - 1];
    float nbr = (w == 4) ? S5 * z[4] : sg[w + 1] * z[w];
    phi -= 2.f * sg[w] * (h[w] + nbl + nbr);
    sg[w] = -sg[w];
    emit(jj ^ (jj >> 1), phi);
  }
}

// ---------------------------------------------------------------------------
// K3: quadrant split-K MFMA GEMM. 512 blocks x 512 threads (8 waves,
// 64KB LDS -> 2 blocks/CU). Each block computes one 128x128 quadrant of C
// over a private K-slab, staging each kb ONCE as one contiguous chunk
// (A and B operands are rows of the same staged block -> 1x Ach read,
// vs R8's 3-tile 2-panel layout which re-read ~3x).
//   b in [0,128):   qt0 = (0:128, 0:128)   diag, kbPer=32, chunk 16KB (rows 0-127)
//   b in [128,384): qt1 = (0:128, 128:256) off,  kbPer=16, chunk 32KB (all rows)
//   b in [384,512): qt2 = (128:256,128:256)diag, kbPer=32, chunk 16KB (rows 128-255)
// Wave w: rows (w>>1)*32 + fr*16 (fr 0..1), cols (w&1)*64 + fc*16 (fc 0..3).
// Partials P[b][plane][128][128] f32 (67 MB).
// ---------------------------------------------------------------------------
__global__ __launch_bounds__(512) void k_gemm_q(const _Float16* __restrict__ A,
                                                float* __restrict__ P) {
  __shared__ _Float16 lds[2][16384];  // 2 x 32 KB
  int b = blockIdx.x;
  int qt = (b < 128) ? 0 : (b < 384 ? 1 : 2);
  int z = b - ((qt == 0) ? 0 : (qt == 1) ? 128 : 384);
  int kbPer = (qt == 1) ? 16 : 32;
  int kb0 = z * kbPer;
  int chunkOff = (qt == 2) ? 16384 : 0;  // byte offset into the kb
  int bRowBase = (qt == 1) ? 128 : 0;    // B rows' local base in staged chunk
  int t = threadIdx.x, wave = t >> 6, lane = t & 63;
  // batch sign: kb < 2048 -> batch x1 (+), else x0 (-). kb0 slab-aligned.
  unsigned int reMask = (kb0 < 2048) ? 0u : 0x80008000u;
  unsigned int imMask = (kb0 < 2048) ? 0x80000000u : 0x00008000u;

  auto stage = [&](int it, int buf) {
    const char* g = (const char*)A + (size_t)(kb0 + it) * 32768 + chunkOff;
    char* l = (char*)&lds[buf][0];
    load16_lds(g + t * 16, l + t * 16);
    load16_lds(g + 8192 + t * 16, l + 8192 + t * 16);
    if (qt == 1) {
      load16_lds(g + 16384 + t * 16, l + 16384 + t * 16);
      load16_lds(g + 24576 + t * 16, l + 24576 + t * 16);
    }
  };

  f32x4 accR[2][4] = {};
  f32x4 accI[2][4] = {};
  stage(0, 0);
  for (int it = 0; it < kbPer; ++it) {
    __syncthreads();  // stage(it) done; everyone done with buf[(it+1)&1]
    if (it + 1 < kbPer) stage(it + 1, (it + 1) & 1);
    int buf = it & 1;
#pragma unroll
    for (int kk = 0; kk < 2; kk++) {
      int cb = kk * 4 + (lane >> 4);
      half8 af[2];
#pragma unroll
      for (int fr = 0; fr < 2; fr++) {
        int r = (wave >> 1) * 32 + fr * 16 + (lane & 15);
        af[fr] = *(const half8*)&lds[buf][r * 64 + ((cb ^ (r & 7)) << 3)];
      }
#pragma unroll
      for (int fc = 0; fc < 4; fc++) {
        int rb = bRowBase + (wave & 1) * 64 + fc * 16 + (lane & 15);
        half8 bv = *(const half8*)&lds[buf][rb * 64 + ((cb ^ (rb & 7)) << 3)];
        U4 u = __builtin_bit_cast(U4, bv), ur, ui;
#pragma unroll
        for (int q = 0; q < 4; q++) {
          unsigned int xv = u.w[q];
          ur.w[q] = xv ^ reMask;
          ui.w[q] = ((xv << 16) | (xv >> 16)) ^ imMask;
        }
        half8 bfr = __builtin_bit_cast(half8, ur);
        half8 bfi = __builtin_bit_cast(half8, ui);
#pragma unroll
        for (int fr = 0; fr < 2; fr++) {
          accR[fr][fc] = __builtin_amdgcn_mfma_f32_16x16x32_f16(
              af[fr], bfr, accR[fr][fc], 0, 0, 0);
          accI[fr][fc] = __builtin_amdgcn_mfma_f32_16x16x32_f16(
              af[fr], bfi, accI[fr][fc], 0, 0, 0);
        }
      }
    }
  }
  float* PR = P + (size_t)b * 32768;
  float* PI = PR + 16384;
  int r4 = (lane >> 4) * 4, cj = lane & 15;
#pragma unroll
  for (int fr = 0; fr < 2; fr++)
#pragma unroll
    for (int fc = 0; fc < 4; fc++)
#pragma unroll
      for (int r = 0; r < 4; r++) {
        int li = (wave >> 1) * 32 + fr * 16 + r4 + r;
        int lj = (wave & 1) * 64 + fc * 16 + cj;
        PR[li * 128 + lj] = accR[fr][fc][r];
        PI[li * 128 + lj] = accI[fr][fc][r];
      }
}

// ---------------------------------------------------------------------------
// K4a: stage-1 reduce over slab groups. grid (128 rows, 3 qts, 8 groups).
// Q layout: QR at ((g*3+qt)*128+r)*128+c ; QI at +8*3*16384.
// ---------------------------------------------------------------------------
__global__ __launch_bounds__(128) void k_reduce1(const float* __restrict__ P,
                                                 float* __restrict__ Q) {
  int r = blockIdx.x, qt = blockIdx.y, g = blockIdx.z, c = threadIdx.x;
  int nsl = (qt == 1) ? 32 : 16;
  int b0 = ((qt == 0) ? 0 : (qt == 1) ? 128 : 384) + g * nsl;
  float vR = 0.f, vI = 0.f;
  for (int u = 0; u < nsl; u++) {
    const float* base = P + (size_t)(b0 + u) * 32768 + r * 128 + c;
    vR += base[0];
    vI += base[16384];
  }
  size_t qidx = ((size_t)(g * 3 + qt) * 128 + r) * 128 + c;
  Q[qidx] = vR;
  Q[qidx + (size_t)8 * 3 * 16384] = vI;
}

// K4b: stage-2: sum 8 groups, map quadrant->global, Hermitian A + ||A||_F^2.
__global__ __launch_bounds__(128) void k_reduce2(const float* __restrict__ Q,
                                                 float* __restrict__ AR,
                                                 float* __restrict__ AI,
                                                 float* __restrict__ sumsq,
                                                 float scale) {
  int r = blockIdx.x, qt = blockIdx.y, c = threadIdx.x;
  float vR = 0.f, vI = 0.f;
#pragma unroll
  for (int g = 0; g < 8; g++) {
    size_t qidx = ((size_t)(g * 3 + qt) * 128 + r) * 128 + c;
    vR += Q[qidx];
    vI += Q[qidx + (size_t)8 * 3 * 16384];
  }
  vR *= scale;
  vI *= scale;
  int i = (qt == 2) ? 128 + r : r;
  int j = (qt == 0) ? c : 128 + c;
  float ss = 0.f;
  bool diagQ = (qt != 1);
  if (!diagQ || c > r) {
    AR[i * 256 + j] = vR;
    AR[j * 256 + i] = vR;
    AI[i * 256 + j] = vI;
    AI[j * 256 + i] = -vI;
    ss = 2.f * (vR * vR + vI * vI);
  } else if (c == r) {
    AR[i * 256 + j] = vR;
    AI[i * 256 + j] = 0.f;
    ss = vR * vR;
  }
#pragma unroll
  for (int o = 32; o > 0; o >>= 1) ss += __shfl_down(ss, o);
  __shared__ float w2[2];
  if ((c & 63) == 0) w2[c >> 6] = ss;
  __syncthreads();
  if (c == 0) atomicAdd(sumsq, w2[0] + w2[1]);
}

// ---------------------------------------------------------------------------
// Newton-Schulz complex matmuls, k-split-4 (R9-proven — do not restructure;
// cooperative single-dispatch variants cost 20-34 us/grid-sync, R10/R11).
// ---------------------------------------------------------------------------
__global__ __launch_bounds__(1024) void k_csq(
    const float* __restrict__ XR, const float* __restrict__ XI,
    float* __restrict__ YR, float* __restrict__ YI,
    float* __restrict__ sumsqY, int accumNorm) {
  __shared__ float rp[16][256][2];
  __shared__ float cpT[16][258][2];
  __shared__ float pacc[3][256][2];
  __shared__ float w16[16];
  int t = threadIdx.x;
  int bi = blockIdx.x >> 4, bj = blockIdx.x & 15;
  {
    int r = t >> 6, c = (t & 63) * 4;
    const float4 vr = *(const float4*)&XR[(bi * 16 + r) * 256 + c];
    const float4 vi = *(const float4*)&XI[(bi * 16 + r) * 256 + c];
    rp[r][c + 0][0] = vr.x; rp[r][c + 1][0] = vr.y;
    rp[r][c + 2][0] = vr.z; rp[r][c + 3][0] = vr.w;
    rp[r][c + 0][1] = vi.x; rp[r][c + 1][1] = vi.y;
    rp[r][c + 2][1] = vi.z; rp[r][c + 3][1] = vi.w;
    int row = t >> 2, c0 = (t & 3) * 4;
    const float4 wr = *(const float4*)&XR[row * 256 + bj * 16 + c0];
    const float4 wi = *(const float4*)&XI[row * 256 + bj * 16 + c0];
    cpT[c0 + 0][row][0] = wr.x; cpT[c0 + 1][row][0] = wr.y;
    cpT[c0 + 2][row][0] = wr.z; cpT[c0 + 3][row][0] = wr.w;
    cpT[c0 + 0][row][1] = wi.x; cpT[c0 + 1][row][1] = wi.y;
    cpT[c0 + 2][row][1] = wi.z; cpT[c0 + 3][row][1] = wi.w;
  }
  __syncthreads();
  int sub = t >> 8, tt = t & 255, ty = tt >> 4, tx = tt & 15;
  float sR = 0.f, sI = 0.f;
  int k0 = sub * 64;
#pragma unroll 8
  for (int k = k0; k < k0 + 64; k++) {
    float xr = rp[ty][k][0], xi = rp[ty][k][1];
    float yr = cpT[tx][k][0], yi = cpT[tx][k][1];
    sR = fmaf(xr, yr, sR);
    sR = fmaf(-xi, yi, sR);
    sI = fmaf(xr, yi, sI);
    sI = fmaf(xi, yr, sI);
  }
  if (sub) {
    pacc[sub - 1][tt][0] = sR;
    pacc[sub - 1][tt][1] = sI;
  }
  __syncthreads();
  float v = 0.f;
  if (sub == 0) {
    sR += (pacc[0][tt][0] + pacc[1][tt][0]) + pacc[2][tt][0];
    sI += (pacc[0][tt][1] + pacc[1][tt][1]) + pacc[2][tt][1];
    int i = bi * 16 + ty, j = bj * 16 + tx;
    YR[i * 256 + j] = sR;
    YI[i * 256 + j] = sI;
    if (accumNorm) v = sR * sR + sI * sI;
  }
#pragma unroll
  for (int o = 32; o > 0; o >>= 1) v += __shfl_down(v, o);
  if ((t & 63) == 0) w16[t >> 6] = v;
  __syncthreads();
  if (t == 0 && accumNorm)
    atomicAdd(sumsqY, (w16[0] + w16[1]) + (w16[2] + w16[3]));
}

// Z = aC*X - bC*(X@Y); same k-split-4 structure.
// mode 0: first iter ON RAW A (norm-folding). mode 1: 2x-x^3. mode 2: 1.5-NS.
// finalTrace: accumulate out += -0.5*sum(A .* Z) instead of writing Z.
__global__ __launch_bounds__(1024) void k_cupd(
    const float* __restrict__ XR, const float* __restrict__ XI,
    const float* __restrict__ YR, const float* __restrict__ YI,
    float* __restrict__ ZR, float* __restrict__ ZI,
    const float* __restrict__ scalars, int mode,
    const float* __restrict__ AR, const float* __restrict__ AI,
    float* __restrict__ out, int finalTrace) {
  __shared__ float rp[16][256][2];
  __shared__ float cpT[16][258][2];
  __shared__ float pacc[3][256][2];
  __shared__ float w16[16];
  int t = threadIdx.x;
  int bi = blockIdx.x >> 4, bj = blockIdx.x & 15;
  {
    int r = t >> 6, c = (t & 63) * 4;
    const float4 vr = *(const float4*)&XR[(bi * 16 + r) * 256 + c];
    const float4 vi = *(const float4*)&XI[(bi * 16 + r) * 256 + c];
    rp[r][c + 0][0] = vr.x; rp[r][c + 1][0] = vr.y;
    rp[r][c + 2][0] = vr.z; rp[r][c + 3][0] = vr.w;
    rp[r][c + 0][1] = vi.x; rp[r][c + 1][1] = vi.y;
    rp[r][c + 2][1] = vi.z; rp[r][c + 3][1] = vi.w;
    int row = t >> 2, c0 = (t & 3) * 4;
    const float4 wr = *(const float4*)&YR[row * 256 + bj * 16 + c0];
    const float4 wi = *(const float4*)&YI[row * 256 + bj * 16 + c0];
    cpT[c0 + 0][row][0] = wr.x; cpT[c0 + 1][row][0] = wr.y;
    cpT[c0 + 2][row][0] = wr.z; cpT[c0 + 3][row][0] = wr.w;
    cpT[c0 + 0][row][1] = wi.x; cpT[c0 + 1][row][1] = wi.y;
    cpT[c0 + 2][row][1] = wi.z; cpT[c0 + 3][row][1] = wi.w;
  }
  __syncthreads();
  int sub = t >> 8, tt = t & 255, ty = tt >> 4, tx = tt & 15;
  float sR = 0.f, sI = 0.f;
  int k0 = sub * 64;
#pragma unroll 8
  for (int k = k0; k < k0 + 64; k++) {
    float xr = rp[ty][k][0], xi = rp[ty][k][1];
    float yr = cpT[tx][k][0], yi = cpT[tx][k][1];
    sR = fmaf(xr, yr, sR);
    sR = fmaf(-xi, yi, sR);
    sI = fmaf(xr, yi, sI);
    sI = fmaf(xi, yr, sI);
  }
  if (sub) {
    pacc[sub - 1][tt][0] = sR;
    pacc[sub - 1][tt][1] = sI;
  }
  __syncthreads();
  float v = 0.f;
  if (sub == 0) {
    sR += (pacc[0][tt][0] + pacc[1][tt][0]) + pacc[2][tt][0];
    sI += (pacc[0][tt][1] + pacc[1][tt][1]) + pacc[2][tt][1];
    float aC, bC;
    if (mode == 0) {
      float f2 = scalars[0];
      float f = sqrtf(f2);
      float Rhat = 1.41421356f * sqrtf(scalars[1]) / f2;
      float g = 1.0f / (1.75f * Rhat);
      aC = 1.5f * g / f;
      float gf = g / f;
      bC = 0.5f * gf * gf * gf;
    } else if (mode == 1) {
      aC = 2.0f;
      bC = 1.0f;
    } else {
      aC = 1.5f;
      bC = 0.5f;
    }
    int idx = (bi * 16 + ty) * 256 + bj * 16 + tx;
    float zr = aC * XR[idx] - bC * sR;
    float zi = aC * XI[idx] - bC * sI;
    if (!finalTrace) {
      ZR[idx] = zr;
      ZI[idx] = zi;
    } else {
      v = AR[idx] * zr + AI[idx] * zi;
    }
  }
#pragma unroll
  for (int o = 32; o > 0; o >>= 1) v += __shfl_down(v, o);
  if ((t & 63) == 0) w16[t >> 6] = v;
  __syncthreads();
  if (t == 0 && finalTrace)
    atomicAdd(out, -0.5f * ((w16[0] + w16[1]) + (w16[2] + w16[3])));
}

// ---------------------------------------------------------------------------
extern "C" void kernel_launch(void* const* d_in, const int* in_sizes, int n_in,
                              void* d_out, int out_size, void* d_ws,
                              size_t ws_size, hipStream_t stream) {
  const float* x1 = (const float*)d_in[0];
  const float* x0 = (const float*)d_in[1];
  const float* W1 = (const float*)d_in[2];
  const float* b1 = (const float*)d_in[3];
  const float* W2 = (const float*)d_in[4];
  const float* b2 = (const float*)d_in[5];
  const float* W3 = (const float*)d_in[6];
  const float* b3 = (const float*)d_in[7];
  (void)n_in;
  (void)out_size;
  (void)ws_size;

  const int B = in_sizes[0] / 8;   // 65536
  const int total = 2 * B;         // 131072
  const int totalKb = total / 32;  // 4096

  char* ws = (char*)d_ws;
  size_t off = 0;
  auto carve = [&](size_t bytes) -> void* {
    off = (off + 255) & ~(size_t)255;
    void* p = ws + off;
    off += bytes;
    return p;
  };
  float* hz = (float*)carve((size_t)total * 16 * 4);              // 8.4 MB
  _Float16* Ach = (_Float16*)carve((size_t)totalKb * 16384 * 2);  // 134 MB
  float* P = (float*)carve((size_t)512 * 32768 * 4);              // 67.1 MB
  float* Q = (float*)carve((size_t)2 * 8 * 3 * 16384 * 4);        // 3.1 MB
  float* scalars = (float*)carve(256);  // [0]=sumsq(A), [1]=sumsq(A^2)
  float* AR = (float*)carve(256 * 256 * 4);
  float* AI = (float*)carve(256 * 256 * 4);
  float* XR = (float*)carve(256 * 256 * 4);
  float* XI = (float*)carve(256 * 256 * 4);
  float* YR = (float*)carve(256 * 256 * 4);
  float* YI = (float*)carve(256 * 256 * 4);
  float* ZR = (float*)carve(256 * 256 * 4);
  float* ZI = (float*)carve(256 * 256 * 4);

  k_mlp<<<(total + 255) / 256, 256, 0, stream>>>(
      x1, x0, W1, b1, W2, b2, W3, b3, hz, B, scalars, (float*)d_out);
  k_gen<<<totalKb, 256, 0, stream>>>(hz, Ach);
  k_gemm_q<<<512, 512, 0, stream>>>(Ach, P);
  k_reduce1<<<dim3(128, 3, 8), 128, 0, stream>>>(P, Q);
  k_reduce2<<<dim3(128, 3), 128, 0, stream>>>(Q, AR, AI, scalars,
                                              1.0f / (256.0f * (float)B));

  // NS schedule (R9-calibrated, absmax 1.22e-4 vs 3.32e-4 threshold):
  // 1x clamp(1.5-NS, rescaled, raw-A norm-folded) + 6x (2x - x^3)
  // + 4x (1.5-NS); trace fused into the last update. Multi-dispatch chain
  // (~5-6 us/launch) beats any gfx950 grid-sync (>=20 us, R10/R11).
  const int NIT = 11;
  float *cR = AR, *cI = AI, *nR = XR, *nI = XI;
  for (int it = 0; it < NIT; it++) {
    int mode = (it == 0) ? 0 : (it <= 6 ? 1 : 2);
    int fin = (it == NIT - 1) ? 1 : 0;
    k_csq<<<256, 1024, 0, stream>>>(cR, cI, YR, YI, scalars + 1, it == 0);
    k_cupd<<<256, 1024, 0, stream>>>(cR, cI, YR, YI, nR, nI, scalars, mode, AR,
                                     AI, (float*)d_out, fin);
    if (it == 0) {
      cR = XR; cI = XI; nR = ZR; nI = ZI;
    } else {
      std::swap(cR, nR);
      std::swap(cI, nI);
    }
  }
}

// Round 13
// 229.052 us; speedup vs baseline: 3.9146x; 1.1045x over previous
//
#include <hip/hip_runtime.h>
#include <cstdint>
#include <cstddef>
#include <utility>

#define PI_F 3.14159265358979323846f

typedef __attribute__((ext_vector_type(8))) _Float16 half8;
typedef __attribute__((ext_vector_type(4))) float f32x4;

struct U4 { unsigned int w[4]; };

static __device__ __forceinline__ unsigned int packhalf2(float c, float s) {
  _Float16 hc = (_Float16)c, hs = (_Float16)s;
  unsigned short uc = __builtin_bit_cast(unsigned short, hc);
  unsigned short us = __builtin_bit_cast(unsigned short, hs);
  return (unsigned int)uc | ((unsigned int)us << 16);
}

static __device__ __forceinline__ void load16_lds(const void* g, void* l) {
  __builtin_amdgcn_global_load_lds(
      (const __attribute__((address_space(1))) unsigned int*)g,
      (__attribute__((address_space(3))) unsigned int*)l, 16, 0, 0);
}

// ---------------------------------------------------------------------------
// K2 (now includes the MLP): block kb handles samples 32kb..32kb+31.
// Threads 0-31 run the per-sample MLP into hzl (h[0..7], z[0..6]); then all
// 256 threads emit the fp16 (cos,sin) pairs. A layout: [kb][256 rows][64
// halfs], 16B chunks XOR-swizzled by (row&7). Gray-code walk + HW v_sin/cos.
// Block 0 thread 0 zero-inits scalars + out (replaces memset dispatches).
// ---------------------------------------------------------------------------
__global__ __launch_bounds__(256) void k_gen(
    const float* __restrict__ x1, const float* __restrict__ x0,
    const float* __restrict__ W1, const float* __restrict__ b1,
    const float* __restrict__ W2, const float* __restrict__ b2,
    const float* __restrict__ W3, const float* __restrict__ b3, int B,
    _Float16* __restrict__ Ach, float* __restrict__ scalars,
    float* __restrict__ out) {
  __shared__ float hzl[32][17];
  int kb = blockIdx.x, t = threadIdx.x;
  if (kb == 0 && t == 0) {
    scalars[0] = 0.f;
    scalars[1] = 0.f;
    out[0] = 0.f;
  }
  if (t < 32) {
    int smp = kb * 32 + t;
    const float* xp =
        (smp < B) ? (x1 + (size_t)smp * 8) : (x0 + (size_t)(smp - B) * 8);
    float x[8];
#pragma unroll
    for (int k = 0; k < 8; k++) x[k] = xp[k];
    float a1[10];
#pragma unroll
    for (int o = 0; o < 10; o++) {
      float v = b1[o];
#pragma unroll
      for (int k = 0; k < 8; k++) v = fmaf(W1[o * 8 + k], x[k], v);
      a1[o] = fmaxf(v, 0.f);
    }
    float a2[10];
#pragma unroll
    for (int o = 0; o < 10; o++) {
      float v = b2[o];
#pragma unroll
      for (int k = 0; k < 10; k++) v = fmaf(W2[o * 10 + k], a1[k], v);
      a2[o] = fmaxf(v, 0.f);
    }
    float hh[8];
#pragma unroll
    for (int o = 0; o < 8; o++) {
      float v = b3[o];
#pragma unroll
      for (int k = 0; k < 10; k++) v = fmaf(W3[o * 10 + k], a2[k], v);
      hh[o] = v;
    }
#pragma unroll
    for (int k = 0; k < 8; k++) hzl[t][k] = hh[k];
#pragma unroll
    for (int k = 0; k < 7; k++)
      hzl[t][8 + k] = (PI_F - hh[k]) * (PI_F - hh[k + 1]);
  }
  __syncthreads();
  int s = t & 31, oct = t >> 5;
  float h[8], z[7];
#pragma unroll
  for (int k = 0; k < 8; k++) h[k] = hzl[s][k];
#pragma unroll
  for (int k = 0; k < 7; k++) z[k] = hzl[s][8 + k];
  float S5 = (oct & 4) ? -1.f : 1.f;
  float S6 = (oct & 2) ? -1.f : 1.f;
  float S7 = (oct & 1) ? -1.f : 1.f;
  float sg[5] = {1.f, 1.f, 1.f, 1.f, 1.f};
  float phi = h[0] + h[1] + h[2] + h[3] + h[4] + S5 * h[5] + S6 * h[6] +
              S7 * h[7] + z[0] + z[1] + z[2] + z[3] + S5 * z[4] +
              S5 * S6 * z[5] + S6 * S7 * z[6];
  _Float16* dst = Ach + (size_t)kb * 16384;
  const int halfoff = (2 * s) ^ (oct << 3);

  auto emit = [&](int g, float ph) {
    float r = ph * 0.07957747154594767f;  // ph/(4*pi) revolutions
    r = r - floorf(r);
    float sv = __builtin_amdgcn_sinf(r);
    float cv = __builtin_amdgcn_cosf(r);
    *(unsigned int*)(dst + (size_t)(g * 8 + oct) * 64 + halfoff) =
        packhalf2(cv, sv);
  };

  emit(0, phi);
#pragma unroll
  for (int jj = 1; jj < 32; ++jj) {
    const int b = __builtin_ctz(jj);
    const int w = 4 - b;
    float nbl = (w == 0) ? 0.f : sg[w - 1] * z[w - 1];
    float nbr = (w == 4) ? S5 * z[4] : sg[w + 1] * z[w];
    phi -= 2.f * sg[w] * (h[w] + nbl + nbr);
    sg[w] = -sg[w];
    emit(jj ^ (jj >> 1), phi);
  }
}

// ---------------------------------------------------------------------------
// K3: quadrant split-K MFMA GEMM. 512 blocks x 512 threads (8 waves,
// 64KB LDS -> 2 blocks/CU). Each block computes one 128x128 quadrant of C
// over a private K-slab, staging each kb ONCE as one contiguous chunk.
//   b in [0,128):   qt0 = (0:128, 0:128)   diag, kbPer=32, chunk 16KB
//   b in [128,384): qt1 = (0:128, 128:256) off,  kbPer=16, chunk 32KB
//   b in [384,512): qt2 = (128:256,128:256)diag, kbPer=32, chunk 16KB
// Partials P[b][plane][128][128] f32 (67 MB).
// ---------------------------------------------------------------------------
__global__ __launch_bounds__(512) void k_gemm_q(const _Float16* __restrict__ A,
                                                float* __restrict__ P) {
  __shared__ _Float16 lds[2][16384];  // 2 x 32 KB
  int b = blockIdx.x;
  int qt = (b < 128) ? 0 : (b < 384 ? 1 : 2);
  int z = b - ((qt == 0) ? 0 : (qt == 1) ? 128 : 384);
  int kbPer = (qt == 1) ? 16 : 32;
  int kb0 = z * kbPer;
  int chunkOff = (qt == 2) ? 16384 : 0;
  int bRowBase = (qt == 1) ? 128 : 0;
  int t = threadIdx.x, wave = t >> 6, lane = t & 63;
  unsigned int reMask = (kb0 < 2048) ? 0u : 0x80008000u;
  unsigned int imMask = (kb0 < 2048) ? 0x80000000u : 0x00008000u;

  auto stage = [&](int it, int buf) {
    const char* g = (const char*)A + (size_t)(kb0 + it) * 32768 + chunkOff;
    char* l = (char*)&lds[buf][0];
    load16_lds(g + t * 16, l + t * 16);
    load16_lds(g + 8192 + t * 16, l + 8192 + t * 16);
    if (qt == 1) {
      load16_lds(g + 16384 + t * 16, l + 16384 + t * 16);
      load16_lds(g + 24576 + t * 16, l + 24576 + t * 16);
    }
  };

  f32x4 accR[2][4] = {};
  f32x4 accI[2][4] = {};
  stage(0, 0);
  for (int it = 0; it < kbPer; ++it) {
    __syncthreads();
    if (it + 1 < kbPer) stage(it + 1, (it + 1) & 1);
    int buf = it & 1;
#pragma unroll
    for (int kk = 0; kk < 2; kk++) {
      int cb = kk * 4 + (lane >> 4);
      half8 af[2];
#pragma unroll
      for (int fr = 0; fr < 2; fr++) {
        int r = (wave >> 1) * 32 + fr * 16 + (lane & 15);
        af[fr] = *(const half8*)&lds[buf][r * 64 + ((cb ^ (r & 7)) << 3)];
      }
#pragma unroll
      for (int fc = 0; fc < 4; fc++) {
        int rb = bRowBase + (wave & 1) * 64 + fc * 16 + (lane & 15);
        half8 bv = *(const half8*)&lds[buf][rb * 64 + ((cb ^ (rb & 7)) << 3)];
        U4 u = __builtin_bit_cast(U4, bv), ur, ui;
#pragma unroll
        for (int q = 0; q < 4; q++) {
          unsigned int xv = u.w[q];
          ur.w[q] = xv ^ reMask;
          ui.w[q] = ((xv << 16) | (xv >> 16)) ^ imMask;
        }
        half8 bfr = __builtin_bit_cast(half8, ur);
        half8 bfi = __builtin_bit_cast(half8, ui);
#pragma unroll
        for (int fr = 0; fr < 2; fr++) {
          accR[fr][fc] = __builtin_amdgcn_mfma_f32_16x16x32_f16(
              af[fr], bfr, accR[fr][fc], 0, 0, 0);
          accI[fr][fc] = __builtin_amdgcn_mfma_f32_16x16x32_f16(
              af[fr], bfi, accI[fr][fc], 0, 0, 0);
        }
      }
    }
  }
  float* PR = P + (size_t)b * 32768;
  float* PI = PR + 16384;
  int r4 = (lane >> 4) * 4, cj = lane & 15;
#pragma unroll
  for (int fr = 0; fr < 2; fr++)
#pragma unroll
    for (int fc = 0; fc < 4; fc++)
#pragma unroll
      for (int r = 0; r < 4; r++) {
        int li = (wave >> 1) * 32 + fr * 16 + r4 + r;
        int lj = (wave & 1) * 64 + fc * 16 + cj;
        PR[li * 128 + lj] = accR[fr][fc][r];
        PI[li * 128 + lj] = accI[fr][fc][r];
      }
}

// ---------------------------------------------------------------------------
// K4a: stage-1 reduce over slab groups. grid (128 rows, 3 qts, 8 groups).
// ---------------------------------------------------------------------------
__global__ __launch_bounds__(128) void k_reduce1(const float* __restrict__ P,
                                                 float* __restrict__ Q) {
  int r = blockIdx.x, qt = blockIdx.y, g = blockIdx.z, c = threadIdx.x;
  int nsl = (qt == 1) ? 32 : 16;
  int b0 = ((qt == 0) ? 0 : (qt == 1) ? 128 : 384) + g * nsl;
  float vR = 0.f, vI = 0.f;
  for (int u = 0; u < nsl; u++) {
    const float* base = P + (size_t)(b0 + u) * 32768 + r * 128 + c;
    vR += base[0];
    vI += base[16384];
  }
  size_t qidx = ((size_t)(g * 3 + qt) * 128 + r) * 128 + c;
  Q[qidx] = vR;
  Q[qidx + (size_t)8 * 3 * 16384] = vI;
}

// K4b: stage-2: sum 8 groups, map quadrant->global, Hermitian A + ||A||_F^2.
__global__ __launch_bounds__(128) void k_reduce2(const float* __restrict__ Q,
                                                 float* __restrict__ AR,
                                                 float* __restrict__ AI,
                                                 float* __restrict__ sumsq,
                                                 float scale) {
  int r = blockIdx.x, qt = blockIdx.y, c = threadIdx.x;
  float vR = 0.f, vI = 0.f;
#pragma unroll
  for (int g = 0; g < 8; g++) {
    size_t qidx = ((size_t)(g * 3 + qt) * 128 + r) * 128 + c;
    vR += Q[qidx];
    vI += Q[qidx + (size_t)8 * 3 * 16384];
  }
  vR *= scale;
  vI *= scale;
  int i = (qt == 2) ? 128 + r : r;
  int j = (qt == 0) ? c : 128 + c;
  float ss = 0.f;
  bool diagQ = (qt != 1);
  if (!diagQ || c > r) {
    AR[i * 256 + j] = vR;
    AR[j * 256 + i] = vR;
    AI[i * 256 + j] = vI;
    AI[j * 256 + i] = -vI;
    ss = 2.f * (vR * vR + vI * vI);
  } else if (c == r) {
    AR[i * 256 + j] = vR;
    AI[i * 256 + j] = 0.f;
    ss = vR * vR;
  }
#pragma unroll
  for (int o = 32; o > 0; o >>= 1) ss += __shfl_down(ss, o);
  __shared__ float w2[2];
  if ((c & 63) == 0) w2[c >> 6] = ss;
  __syncthreads();
  if (c == 0) atomicAdd(sumsq, w2[0] + w2[1]);
}

// ---------------------------------------------------------------------------
// Newton-Schulz complex matmuls, k-split-4 (R9-proven structure).
// rp padded to [16][258][2]: the [256] stride put all 4 per-wave ty rows in
// one bank (4-way conflict, 1.58x per m136; found via R10's 1.44e7
// SQ_LDS_BANK_CONFLICT). Interleaved vectorized staging (R11 form).
// ---------------------------------------------------------------------------
__global__ __launch_bounds__(1024) void k_csq(
    const float* __restrict__ XR, const float* __restrict__ XI,
    float* __restrict__ YR, float* __restrict__ YI,
    float* __restrict__ sumsqY, int accumNorm) {
  __shared__ float rp[16][258][2];
  __shared__ float cpT[16][258][2];
  __shared__ float pacc[3][256][2];
  __shared__ float w16[16];
  int t = threadIdx.x;
  int bi = blockIdx.x >> 4, bj = blockIdx.x & 15;
  {
    int r = t >> 6, c = (t & 63) * 4;
    const float4 vr = *(const float4*)&XR[(bi * 16 + r) * 256 + c];
    const float4 vi = *(const float4*)&XI[(bi * 16 + r) * 256 + c];
    float4 p0 = {vr.x, vi.x, vr.y, vi.y};
    float4 p1 = {vr.z, vi.z, vr.w, vi.w};
    *(float4*)&rp[r][c][0] = p0;
    *(float4*)&rp[r][c + 2][0] = p1;
    int row = t >> 2, c0 = (t & 3) * 4;
    const float4 wr = *(const float4*)&XR[row * 256 + bj * 16 + c0];
    const float4 wi = *(const float4*)&XI[row * 256 + bj * 16 + c0];
    float2 q0 = {wr.x, wi.x}, q1 = {wr.y, wi.y};
    float2 q2 = {wr.z, wi.z}, q3 = {wr.w, wi.w};
    *(float2*)&cpT[c0 + 0][row][0] = q0;
    *(float2*)&cpT[c0 + 1][row][0] = q1;
    *(float2*)&cpT[c0 + 2][row][0] = q2;
    *(float2*)&cpT[c0 + 3][row][0] = q3;
  }
  __syncthreads();
  int sub = t >> 8, tt = t & 255, ty = tt >> 4, tx = tt & 15;
  float sR = 0.f, sI = 0.f;
  int k0 = sub * 64;
#pragma unroll 8
  for (int k = k0; k < k0 + 64; k++) {
    float xr = rp[ty][k][0], xi = rp[ty][k][1];
    float yr = cpT[tx][k][0], yi = cpT[tx][k][1];
    sR = fmaf(xr, yr, sR);
    sR = fmaf(-xi, yi, sR);
    sI = fmaf(xr, yi, sI);
    sI = fmaf(xi, yr, sI);
  }
  if (sub) {
    pacc[sub - 1][tt][0] = sR;
    pacc[sub - 1][tt][1] = sI;
  }
  __syncthreads();
  float v = 0.f;
  if (sub == 0) {
    sR += (pacc[0][tt][0] + pacc[1][tt][0]) + pacc[2][tt][0];
    sI += (pacc[0][tt][1] + pacc[1][tt][1]) + pacc[2][tt][1];
    int i = bi * 16 + ty, j = bj * 16 + tx;
    YR[i * 256 + j] = sR;
    YI[i * 256 + j] = sI;
    if (accumNorm) v = sR * sR + sI * sI;
  }
#pragma unroll
  for (int o = 32; o > 0; o >>= 1) v += __shfl_down(v, o);
  if ((t & 63) == 0) w16[t >> 6] = v;
  __syncthreads();
  if (t == 0 && accumNorm)
    atomicAdd(sumsqY, (w16[0] + w16[1]) + (w16[2] + w16[3]));
}

// Z = aC*X - bC*(X@Y); same structure.
// mode 0: first iter ON RAW A (norm-folding). mode 1: 2x-x^3. mode 2: 1.5-NS.
// finalTrace: accumulate out += -0.5*sum(A .* Z) instead of writing Z.
__global__ __launch_bounds__(1024) void k_cupd(
    const float* __restrict__ XR, const float* __restrict__ XI,
    const float* __restrict__ YR, const float* __restrict__ YI,
    float* __restrict__ ZR, float* __restrict__ ZI,
    const float* __restrict__ scalars, int mode,
    const float* __restrict__ AR, const float* __restrict__ AI,
    float* __restrict__ out, int finalTrace) {
  __shared__ float rp[16][258][2];
  __shared__ float cpT[16][258][2];
  __shared__ float pacc[3][256][2];
  __shared__ float w16[16];
  int t = threadIdx.x;
  int bi = blockIdx.x >> 4, bj = blockIdx.x & 15;
  {
    int r = t >> 6, c = (t & 63) * 4;
    const float4 vr = *(const float4*)&XR[(bi * 16 + r) * 256 + c];
    const float4 vi = *(const float4*)&XI[(bi * 16 + r) * 256 + c];
    float4 p0 = {vr.x, vi.x, vr.y, vi.y};
    float4 p1 = {vr.z, vi.z, vr.w, vi.w};
    *(float4*)&rp[r][c][0] = p0;
    *(float4*)&rp[r][c + 2][0] = p1;
    int row = t >> 2, c0 = (t & 3) * 4;
    const float4 wr = *(const float4*)&YR[row * 256 + bj * 16 + c0];
    const float4 wi = *(const float4*)&YI[row * 256 + bj * 16 + c0];
    float2 q0 = {wr.x, wi.x}, q1 = {wr.y, wi.y};
    float2 q2 = {wr.z, wi.z}, q3 = {wr.w, wi.w};
    *(float2*)&cpT[c0 + 0][row][0] = q0;
    *(float2*)&cpT[c0 + 1][row][0] = q1;
    *(float2*)&cpT[c0 + 2][row][0] = q2;
    *(float2*)&cpT[c0 + 3][row][0] = q3;
  }
  __syncthreads();
  int sub = t >> 8, tt = t & 255, ty = tt >> 4, tx = tt & 15;
  float sR = 0.f, sI = 0.f;
  int k0 = sub * 64;
#pragma unroll 8
  for (int k = k0; k < k0 + 64; k++) {
    float xr = rp[ty][k][0], xi = rp[ty][k][1];
    float yr = cpT[tx][k][0], yi = cpT[tx][k][1];
    sR = fmaf(xr, yr, sR);
    sR = fmaf(-xi, yi, sR);
    sI = fmaf(xr, yi, sI);
    sI = fmaf(xi, yr, sI);
  }
  if (sub) {
    pacc[sub - 1][tt][0] = sR;
    pacc[sub - 1][tt][1] = sI;
  }
  __syncthreads();
  float v = 0.f;
  if (sub == 0) {
    sR += (pacc[0][tt][0] + pacc[1][tt][0]) + pacc[2][tt][0];
    sI += (pacc[0][tt][1] + pacc[1][tt][1]) + pacc[2][tt][1];
    float aC, bC;
    if (mode == 0) {
      float f2 = scalars[0];
      float f = sqrtf(f2);
      float Rhat = 1.41421356f * sqrtf(scalars[1]) / f2;
      float g = 1.0f / (1.75f * Rhat);
      aC = 1.5f * g / f;
      float gf = g / f;
      bC = 0.5f * gf * gf * gf;
    } else if (mode == 1) {
      aC = 2.0f;
      bC = 1.0f;
    } else {
      aC = 1.5f;
      bC = 0.5f;
    }
    int idx = (bi * 16 + ty) * 256 + bj * 16 + tx;
    float zr = aC * XR[idx] - bC * sR;
    float zi = aC * XI[idx] - bC * sI;
    if (!finalTrace) {
      ZR[idx] = zr;
      ZI[idx] = zi;
    } else {
      v = AR[idx] * zr + AI[idx] * zi;
    }
  }
#pragma unroll
  for (int o = 32; o > 0; o >>= 1) v += __shfl_down(v, o);
  if ((t & 63) == 0) w16[t >> 6] = v;
  __syncthreads();
  if (t == 0 && finalTrace)
    atomicAdd(out, -0.5f * ((w16[0] + w16[1]) + (w16[2] + w16[3])));
}

// ---------------------------------------------------------------------------
extern "C" void kernel_launch(void* const* d_in, const int* in_sizes, int n_in,
                              void* d_out, int out_size, void* d_ws,
                              size_t ws_size, hipStream_t stream) {
  const float* x1 = (const float*)d_in[0];
  const float* x0 = (const float*)d_in[1];
  const float* W1 = (const float*)d_in[2];
  const float* b1 = (const float*)d_in[3];
  const float* W2 = (const float*)d_in[4];
  const float* b2 = (const float*)d_in[5];
  const float* W3 = (const float*)d_in[6];
  const float* b3 = (const float*)d_in[7];
  (void)n_in;
  (void)out_size;
  (void)ws_size;

  const int B = in_sizes[0] / 8;   // 65536
  const int total = 2 * B;         // 131072
  const int totalKb = total / 32;  // 4096

  char* ws = (char*)d_ws;
  size_t off = 0;
  auto carve = [&](size_t bytes) -> void* {
    off = (off + 255) & ~(size_t)255;
    void* p = ws + off;
    off += bytes;
    return p;
  };
  _Float16* Ach = (_Float16*)carve((size_t)totalKb * 16384 * 2);  // 134 MB
  float* P = (float*)carve((size_t)512 * 32768 * 4);              // 67.1 MB
  float* Q = (float*)carve((size_t)2 * 8 * 3 * 16384 * 4);        // 3.1 MB
  float* scalars = (float*)carve(256);  // [0]=sumsq(A), [1]=sumsq(A^2)
  float* AR = (float*)carve(256 * 256 * 4);
  float* AI = (float*)carve(256 * 256 * 4);
  float* XR = (float*)carve(256 * 256 * 4);
  float* XI = (float*)carve(256 * 256 * 4);
  float* YR = (float*)carve(256 * 256 * 4);
  float* YI = (float*)carve(256 * 256 * 4);
  float* ZR = (float*)carve(256 * 256 * 4);
  float* ZI = (float*)carve(256 * 256 * 4);

  k_gen<<<totalKb, 256, 0, stream>>>(x1, x0, W1, b1, W2, b2, W3, b3, B, Ach,
                                     scalars, (float*)d_out);
  k_gemm_q<<<512, 512, 0, stream>>>(Ach, P);
  k_reduce1<<<dim3(128, 3, 8), 128, 0, stream>>>(P, Q);
  k_reduce2<<<dim3(128, 3), 128, 0, stream>>>(Q, AR, AI, scalars,
                                              1.0f / (256.0f * (float)B));

  // NS schedule (R9-calibrated, absmax 1.22e-4 vs 3.32e-4 threshold; err
  // model ~9.4/M^2 with M=278 — do NOT shorten):
  // 1x clamp(1.5-NS, rescaled, raw-A norm-folded) + 6x (2x - x^3)
  // + 4x (1.5-NS); trace fused into the last update. Multi-dispatch chain
  // (~5-6 us/launch) beats any gfx950 grid-sync (>=20 us, R10/R11).
  const int NIT = 11;
  float *cR = AR, *cI = AI, *nR = XR, *nI = XI;
  for (int it = 0; it < NIT; it++) {
    int mode = (it == 0) ? 0 : (it <= 6 ? 1 : 2);
    int fin = (it == NIT - 1) ? 1 : 0;
    k_csq<<<256, 1024, 0, stream>>>(cR, cI, YR, YI, scalars + 1, it == 0);
    k_cupd<<<256, 1024, 0, stream>>>(cR, cI, YR, YI, nR, nI, scalars, mode, AR,
                                     AI, (float*)d_out, fin);
    if (it == 0) {
      cR = XR; cI = XI; nR = ZR; nI = ZI;
    } else {
      std::swap(cR, nR);
      std::swap(cI, nI);
    }
  }
}

// Round 14
// 219.222 us; speedup vs baseline: 4.0901x; 1.0448x over previous
//
#include <hip/hip_runtime.h>
#include <cstdint>
#include <cstddef>
#include <utility>

#define PI_F 3.14159265358979323846f

typedef __attribute__((ext_vector_type(8))) _Float16 half8;
typedef __attribute__((ext_vector_type(4))) float f32x4;

struct U4 { unsigned int w[4]; };

static __device__ __forceinline__ unsigned int packhalf2(float c, float s) {
  _Float16 hc = (_Float16)c, hs = (_Float16)s;
  unsigned short uc = __builtin_bit_cast(unsigned short, hc);
  unsigned short us = __builtin_bit_cast(unsigned short, hs);
  return (unsigned int)uc | ((unsigned int)us << 16);
}

// ---------------------------------------------------------------------------
// K1: MLP for all 2B samples -> hz[sample][16] = {h[0..7], z[0..6], 0}.
// Block 0 thread 0 also zero-inits scalars + out.
// ---------------------------------------------------------------------------
__global__ __launch_bounds__(256) void k_mlp(
    const float* __restrict__ x1, const float* __restrict__ x0,
    const float* __restrict__ W1, const float* __restrict__ b1,
    const float* __restrict__ W2, const float* __restrict__ b2,
    const float* __restrict__ W3, const float* __restrict__ b3,
    float* __restrict__ hz, int B, float* __restrict__ scalars,
    float* __restrict__ out) {
  int s = blockIdx.x * blockDim.x + threadIdx.x;
  if (blockIdx.x == 0 && threadIdx.x == 0) {
    scalars[0] = 0.f;
    scalars[1] = 0.f;
    out[0] = 0.f;
  }
  if (s >= 2 * B) return;
  const float* xp = (s < B) ? (x1 + (size_t)s * 8) : (x0 + (size_t)(s - B) * 8);
  float x[8];
#pragma unroll
  for (int k = 0; k < 8; k++) x[k] = xp[k];
  float a1[10];
#pragma unroll
  for (int o = 0; o < 10; o++) {
    float v = b1[o];
#pragma unroll
    for (int k = 0; k < 8; k++) v = fmaf(W1[o * 8 + k], x[k], v);
    a1[o] = fmaxf(v, 0.f);
  }
  float a2[10];
#pragma unroll
  for (int o = 0; o < 10; o++) {
    float v = b2[o];
#pragma unroll
    for (int k = 0; k < 10; k++) v = fmaf(W2[o * 10 + k], a1[k], v);
    a2[o] = fmaxf(v, 0.f);
  }
  float h[8];
#pragma unroll
  for (int o = 0; o < 8; o++) {
    float v = b3[o];
#pragma unroll
    for (int k = 0; k < 10; k++) v = fmaf(W3[o * 10 + k], a2[k], v);
    h[o] = v;
  }
  float outv[16];
#pragma unroll
  for (int k = 0; k < 8; k++) outv[k] = h[k];
#pragma unroll
  for (int k = 0; k < 7; k++) outv[8 + k] = (PI_F - h[k]) * (PI_F - h[k + 1]);
  outv[15] = 0.f;
  float4* dst = (float4*)(hz + (size_t)s * 16);
#pragma unroll
  for (int q = 0; q < 4; q++) dst[q] = ((float4*)outv)[q];
}

// ---------------------------------------------------------------------------
// K3: FUSED gen+GEMM. 512 blocks x 512 threads. Each block computes one
// 128x128 quadrant over a private K-slab; the fp16 (cos,sin) chunk for
// kb it+1 is GENERATED IN-LDS (Gray-code walk + HW v_sin/v_cos) while the
// MFMA consumes chunk it — no Ach array, no global staging, no vmcnt-drain
// stall (VALU gen and MFMA co-issue on separate pipes, m114). Layout in
// LDS is identical to the old Ach chunk (rows x 64 halfs, 16B groups
// XOR-swizzled by row&7) so the MFMA read path is unchanged (proven).
//   b in [0,128):   qt0 (0:128,0:128)    diag, kbPer=32, jj walk [0,16)
//   b in [128,384): qt1 (0:128,128:256)  off,  kbPer=16, jj walk [0,32)
//   b in [384,512): qt2 (128:256,128:256)diag, kbPer=32, jj walk [16,32)
// (Gray g = jj^(jj>>1): bit4(g)=bit4(jj), so jj<16 <-> row<128.)
// Thread map: s=t&31 (sample), octH=t>>5: oct=octH&7, jHalf=octH>>3.
// Partials P[b][plane][128][128] f32 (67 MB).
// ---------------------------------------------------------------------------
__global__ __launch_bounds__(512) void k_gemm_f(const float* __restrict__ hz,
                                                float* __restrict__ P) {
  __shared__ _Float16 lds[2][16384];  // 2 x 32 KB chunk buffers
  __shared__ float hzb[2][32][17];    // double-buffered hz rows (padded)
  int b = blockIdx.x;
  int qt = (b < 128) ? 0 : (b < 384 ? 1 : 2);
  int z = b - ((qt == 0) ? 0 : (qt == 1) ? 128 : 384);
  int kbPer = (qt == 1) ? 16 : 32;
  int kb0 = z * kbPer;
  int rowLocalBase = (qt == 2) ? 128 : 0;  // global row - local row
  int bRowBase = (qt == 1) ? 128 : 0;      // B-operand local row base
  int t = threadIdx.x, wave = t >> 6, lane = t & 63;
  unsigned int reMask = (kb0 < 2048) ? 0u : 0x80008000u;
  unsigned int imMask = (kb0 < 2048) ? 0x80000000u : 0x00008000u;

  int s = t & 31, octH = t >> 5;
  int oct = octH & 7, jHalf = octH >> 3;
  const int nJ = (qt == 1) ? 16 : 8;
  const int jj0 = (qt == 1) ? jHalf * 16 : ((qt == 2) ? 16 : 0) + jHalf * 8;
  const int halfoff = (2 * s) ^ (oct << 3);
  const float S5 = (oct & 4) ? -1.f : 1.f;
  const float S6 = (oct & 2) ? -1.f : 1.f;
  const float S7 = (oct & 1) ? -1.f : 1.f;

  auto loadHz = [&](int kb) {
    if (t < 128) {
      int smp = t >> 2, q = t & 3;
      const float4 v =
          *(const float4*)(hz + (size_t)(kb * 32 + smp) * 16 + q * 4);
      float* d = &hzb[kb & 1][smp][q * 4];
      d[0] = v.x;
      d[1] = v.y;
      d[2] = v.z;
      d[3] = v.w;
    }
  };

  // generate chunk kb into lds[buf] (reads hzb[kb&1], loaded last iter)
  auto gen = [&](int kb, int buf) {
    int hb = kb & 1;
    float h[8], z7[7];
#pragma unroll
    for (int k = 0; k < 8; k++) h[k] = hzb[hb][s][k];
#pragma unroll
    for (int k = 0; k < 7; k++) z7[k] = hzb[hb][s][8 + k];
    int g0 = jj0 ^ (jj0 >> 1);
    float sg[5];
#pragma unroll
    for (int w = 0; w < 5; w++) sg[w] = ((g0 >> (4 - w)) & 1) ? -1.f : 1.f;
    float phi = sg[0] * h[0] + sg[1] * h[1] + sg[2] * h[2] + sg[3] * h[3] +
                sg[4] * h[4] + S5 * h[5] + S6 * h[6] + S7 * h[7] +
                sg[0] * sg[1] * z7[0] + sg[1] * sg[2] * z7[1] +
                sg[2] * sg[3] * z7[2] + sg[3] * sg[4] * z7[3] +
                sg[4] * S5 * z7[4] + S5 * S6 * z7[5] + S6 * S7 * z7[6];
    int g = g0;
    auto emitRow = [&](int gg, float ph) {
      int lr = gg * 8 + oct - rowLocalBase;  // local row in chunk
      float r = ph * 0.07957747154594767f;   // ph/(4*pi) revolutions
      r = r - floorf(r);
      float sv = __builtin_amdgcn_sinf(r);
      float cv = __builtin_amdgcn_cosf(r);
      *(unsigned int*)&lds[buf][lr * 64 + halfoff] = packhalf2(cv, sv);
    };
    emitRow(g, phi);
#pragma unroll
    for (int stp = 1; stp < 16; stp++) {
      if (stp >= nJ) break;  // nJ is 8 or 16; unroll fully, break for diag
      const int bbit = __builtin_ctz(stp);  // == ctz(jj0+stp): jj0 % nJ == 0
      const int w = 4 - bbit;
      float nbl = (w == 0) ? 0.f : sg[w - 1] * z7[w - 1];
      float nbr = (w == 4) ? S5 * z7[4] : sg[w + 1] * z7[w];
      phi -= 2.f * sg[w] * (h[w] + nbl + nbr);
      sg[w] = -sg[w];
      g ^= (1 << bbit);
      emitRow(g, phi);
    }
  };

  f32x4 accR[2][4] = {};
  f32x4 accI[2][4] = {};

  // prologue: hz(kb0) -> gen chunk(kb0) -> hz(kb0+1)
  loadHz(kb0);
  __syncthreads();
  gen(kb0, 0);
  loadHz(kb0 + 1);
  __syncthreads();

  for (int it = 0; it < kbPer; ++it) {
    // generate next chunk into the other buffer; prefetch hz two ahead
    if (it + 1 < kbPer) {
      gen(kb0 + it + 1, (it + 1) & 1);
      if (it + 2 < kbPer) loadHz(kb0 + it + 2);
    }
    int buf = it & 1;
#pragma unroll
    for (int kk = 0; kk < 2; kk++) {
      int cb = kk * 4 + (lane >> 4);
      half8 af[2];
#pragma unroll
      for (int fr = 0; fr < 2; fr++) {
        int r = (wave >> 1) * 32 + fr * 16 + (lane & 15);
        af[fr] = *(const half8*)&lds[buf][r * 64 + ((cb ^ (r & 7)) << 3)];
      }
#pragma unroll
      for (int fc = 0; fc < 4; fc++) {
        int rb = bRowBase + (wave & 1) * 64 + fc * 16 + (lane & 15);
        half8 bv = *(const half8*)&lds[buf][rb * 64 + ((cb ^ (rb & 7)) << 3)];
        U4 u = __builtin_bit_cast(U4, bv), ur, ui;
#pragma unroll
        for (int q = 0; q < 4; q++) {
          unsigned int xv = u.w[q];
          ur.w[q] = xv ^ reMask;
          ui.w[q] = ((xv << 16) | (xv >> 16)) ^ imMask;
        }
        half8 bfr = __builtin_bit_cast(half8, ur);
        half8 bfi = __builtin_bit_cast(half8, ui);
#pragma unroll
        for (int fr = 0; fr < 2; fr++) {
          accR[fr][fc] = __builtin_amdgcn_mfma_f32_16x16x32_f16(
              af[fr], bfr, accR[fr][fc], 0, 0, 0);
          accI[fr][fc] = __builtin_amdgcn_mfma_f32_16x16x32_f16(
              af[fr], bfi, accI[fr][fc], 0, 0, 0);
        }
      }
    }
    __syncthreads();  // gen(it+1) writes + MFMA(it) reads complete
  }
  float* PR = P + (size_t)b * 32768;
  float* PI = PR + 16384;
  int r4 = (lane >> 4) * 4, cj = lane & 15;
#pragma unroll
  for (int fr = 0; fr < 2; fr++)
#pragma unroll
    for (int fc = 0; fc < 4; fc++)
#pragma unroll
      for (int r = 0; r < 4; r++) {
        int li = (wave >> 1) * 32 + fr * 16 + r4 + r;
        int lj = (wave & 1) * 64 + fc * 16 + cj;
        PR[li * 128 + lj] = accR[fr][fc][r];
        PI[li * 128 + lj] = accI[fr][fc][r];
      }
}

// ---------------------------------------------------------------------------
// K4a: stage-1 reduce over slab groups. grid (128 rows, 3 qts, 8 groups).
// ---------------------------------------------------------------------------
__global__ __launch_bounds__(128) void k_reduce1(const float* __restrict__ P,
                                                 float* __restrict__ Q) {
  int r = blockIdx.x, qt = blockIdx.y, g = blockIdx.z, c = threadIdx.x;
  int nsl = (qt == 1) ? 32 : 16;
  int b0 = ((qt == 0) ? 0 : (qt == 1) ? 128 : 384) + g * nsl;
  float vR = 0.f, vI = 0.f;
  for (int u = 0; u < nsl; u++) {
    const float* base = P + (size_t)(b0 + u) * 32768 + r * 128 + c;
    vR += base[0];
    vI += base[16384];
  }
  size_t qidx = ((size_t)(g * 3 + qt) * 128 + r) * 128 + c;
  Q[qidx] = vR;
  Q[qidx + (size_t)8 * 3 * 16384] = vI;
}

// K4b: stage-2: sum 8 groups, map quadrant->global, Hermitian A + ||A||_F^2.
__global__ __launch_bounds__(128) void k_reduce2(const float* __restrict__ Q,
                                                 float* __restrict__ AR,
                                                 float* __restrict__ AI,
                                                 float* __restrict__ sumsq,
                                                 float scale) {
  int r = blockIdx.x, qt = blockIdx.y, c = threadIdx.x;
  float vR = 0.f, vI = 0.f;
#pragma unroll
  for (int g = 0; g < 8; g++) {
    size_t qidx = ((size_t)(g * 3 + qt) * 128 + r) * 128 + c;
    vR += Q[qidx];
    vI += Q[qidx + (size_t)8 * 3 * 16384];
  }
  vR *= scale;
  vI *= scale;
  int i = (qt == 2) ? 128 + r : r;
  int j = (qt == 0) ? c : 128 + c;
  float ss = 0.f;
  bool diagQ = (qt != 1);
  if (!diagQ || c > r) {
    AR[i * 256 + j] = vR;
    AR[j * 256 + i] = vR;
    AI[i * 256 + j] = vI;
    AI[j * 256 + i] = -vI;
    ss = 2.f * (vR * vR + vI * vI);
  } else if (c == r) {
    AR[i * 256 + j] = vR;
    AI[i * 256 + j] = 0.f;
    ss = vR * vR;
  }
#pragma unroll
  for (int o = 32; o > 0; o >>= 1) ss += __shfl_down(ss, o);
  __shared__ float w2[2];
  if ((c & 63) == 0) w2[c >> 6] = ss;
  __syncthreads();
  if (c == 0) atomicAdd(sumsq, w2[0] + w2[1]);
}

// ---------------------------------------------------------------------------
// Newton-Schulz complex matmuls, k-split-4 (R9/R13-proven — frozen).
// ---------------------------------------------------------------------------
__global__ __launch_bounds__(1024) void k_csq(
    const float* __restrict__ XR, const float* __restrict__ XI,
    float* __restrict__ YR, float* __restrict__ YI,
    float* __restrict__ sumsqY, int accumNorm) {
  __shared__ float rp[16][258][2];
  __shared__ float cpT[16][258][2];
  __shared__ float pacc[3][256][2];
  __shared__ float w16[16];
  int t = threadIdx.x;
  int bi = blockIdx.x >> 4, bj = blockIdx.x & 15;
  {
    int r = t >> 6, c = (t & 63) * 4;
    const float4 vr = *(const float4*)&XR[(bi * 16 + r) * 256 + c];
    const float4 vi = *(const float4*)&XI[(bi * 16 + r) * 256 + c];
    float4 p0 = {vr.x, vi.x, vr.y, vi.y};
    float4 p1 = {vr.z, vi.z, vr.w, vi.w};
    *(float4*)&rp[r][c][0] = p0;
    *(float4*)&rp[r][c + 2][0] = p1;
    int row = t >> 2, c0 = (t & 3) * 4;
    const float4 wr = *(const float4*)&XR[row * 256 + bj * 16 + c0];
    const float4 wi = *(const float4*)&XI[row * 256 + bj * 16 + c0];
    float2 q0 = {wr.x, wi.x}, q1 = {wr.y, wi.y};
    float2 q2 = {wr.z, wi.z}, q3 = {wr.w, wi.w};
    *(float2*)&cpT[c0 + 0][row][0] = q0;
    *(float2*)&cpT[c0 + 1][row][0] = q1;
    *(float2*)&cpT[c0 + 2][row][0] = q2;
    *(float2*)&cpT[c0 + 3][row][0] = q3;
  }
  __syncthreads();
  int sub = t >> 8, tt = t & 255, ty = tt >> 4, tx = tt & 15;
  float sR = 0.f, sI = 0.f;
  int k0 = sub * 64;
#pragma unroll 8
  for (int k = k0; k < k0 + 64; k++) {
    float xr = rp[ty][k][0], xi = rp[ty][k][1];
    float yr = cpT[tx][k][0], yi = cpT[tx][k][1];
    sR = fmaf(xr, yr, sR);
    sR = fmaf(-xi, yi, sR);
    sI = fmaf(xr, yi, sI);
    sI = fmaf(xi, yr, sI);
  }
  if (sub) {
    pacc[sub - 1][tt][0] = sR;
    pacc[sub - 1][tt][1] = sI;
  }
  __syncthreads();
  float v = 0.f;
  if (sub == 0) {
    sR += (pacc[0][tt][0] + pacc[1][tt][0]) + pacc[2][tt][0];
    sI += (pacc[0][tt][1] + pacc[1][tt][1]) + pacc[2][tt][1];
    int i = bi * 16 + ty, j = bj * 16 + tx;
    YR[i * 256 + j] = sR;
    YI[i * 256 + j] = sI;
    if (accumNorm) v = sR * sR + sI * sI;
  }
#pragma unroll
  for (int o = 32; o > 0; o >>= 1) v += __shfl_down(v, o);
  if ((t & 63) == 0) w16[t >> 6] = v;
  __syncthreads();
  if (t == 0 && accumNorm)
    atomicAdd(sumsqY, (w16[0] + w16[1]) + (w16[2] + w16[3]));
}

// Z = aC*X - bC*(X@Y); same structure.
__global__ __launch_bounds__(1024) void k_cupd(
    const float* __restrict__ XR, const float* __restrict__ XI,
    const float* __restrict__ YR, const float* __restrict__ YI,
    float* __restrict__ ZR, float* __restrict__ ZI,
    const float* __restrict__ scalars, int mode,
    const float* __restrict__ AR, const float* __restrict__ AI,
    float* __restrict__ out, int finalTrace) {
  __shared__ float rp[16][258][2];
  __shared__ float cpT[16][258][2];
  __shared__ float pacc[3][256][2];
  __shared__ float w16[16];
  int t = threadIdx.x;
  int bi = blockIdx.x >> 4, bj = blockIdx.x & 15;
  {
    int r = t >> 6, c = (t & 63) * 4;
    const float4 vr = *(const float4*)&XR[(bi * 16 + r) * 256 + c];
    const float4 vi = *(const float4*)&XI[(bi * 16 + r) * 256 + c];
    float4 p0 = {vr.x, vi.x, vr.y, vi.y};
    float4 p1 = {vr.z, vi.z, vr.w, vi.w};
    *(float4*)&rp[r][c][0] = p0;
    *(float4*)&rp[r][c + 2][0] = p1;
    int row = t >> 2, c0 = (t & 3) * 4;
    const float4 wr = *(const float4*)&YR[row * 256 + bj * 16 + c0];
    const float4 wi = *(const float4*)&YI[row * 256 + bj * 16 + c0];
    float2 q0 = {wr.x, wi.x}, q1 = {wr.y, wi.y};
    float2 q2 = {wr.z, wi.z}, q3 = {wr.w, wi.w};
    *(float2*)&cpT[c0 + 0][row][0] = q0;
    *(float2*)&cpT[c0 + 1][row][0] = q1;
    *(float2*)&cpT[c0 + 2][row][0] = q2;
    *(float2*)&cpT[c0 + 3][row][0] = q3;
  }
  __syncthreads();
  int sub = t >> 8, tt = t & 255, ty = tt >> 4, tx = tt & 15;
  float sR = 0.f, sI = 0.f;
  int k0 = sub * 64;
#pragma unroll 8
  for (int k = k0; k < k0 + 64; k++) {
    float xr = rp[ty][k][0], xi = rp[ty][k][1];
    float yr = cpT[tx][k][0], yi = cpT[tx][k][1];
    sR = fmaf(xr, yr, sR);
    sR = fmaf(-xi, yi, sR);
    sI = fmaf(xr, yi, sI);
    sI = fmaf(xi, yr, sI);
  }
  if (sub) {
    pacc[sub - 1][tt][0] = sR;
    pacc[sub - 1][tt][1] = sI;
  }
  __syncthreads();
  float v = 0.f;
  if (sub == 0) {
    sR += (pacc[0][tt][0] + pacc[1][tt][0]) + pacc[2][tt][0];
    sI += (pacc[0][tt][1] + pacc[1][tt][1]) + pacc[2][tt][1];
    float aC, bC;
    if (mode == 0) {
      float f2 = scalars[0];
      float f = sqrtf(f2);
      float Rhat = 1.41421356f * sqrtf(scalars[1]) / f2;
      float g = 1.0f / (1.75f * Rhat);
      aC = 1.5f * g / f;
      float gf = g / f;
      bC = 0.5f * gf * gf * gf;
    } else if (mode == 1) {
      aC = 2.0f;
      bC = 1.0f;
    } else {
      aC = 1.5f;
      bC = 0.5f;
    }
    int idx = (bi * 16 + ty) * 256 + bj * 16 + tx;
    float zr = aC * XR[idx] - bC * sR;
    float zi = aC * XI[idx] - bC * sI;
    if (!finalTrace) {
      ZR[idx] = zr;
      ZI[idx] = zi;
    } else {
      v = AR[idx] * zr + AI[idx] * zi;
    }
  }
#pragma unroll
  for (int o = 32; o > 0; o >>= 1) v += __shfl_down(v, o);
  if ((t & 63) == 0) w16[t >> 6] = v;
  __syncthreads();
  if (t == 0 && finalTrace)
    atomicAdd(out, -0.5f * ((w16[0] + w16[1]) + (w16[2] + w16[3])));
}

// ---------------------------------------------------------------------------
extern "C" void kernel_launch(void* const* d_in, const int* in_sizes, int n_in,
                              void* d_out, int out_size, void* d_ws,
                              size_t ws_size, hipStream_t stream) {
  const float* x1 = (const float*)d_in[0];
  const float* x0 = (const float*)d_in[1];
  const float* W1 = (const float*)d_in[2];
  const float* b1 = (const float*)d_in[3];
  const float* W2 = (const float*)d_in[4];
  const float* b2 = (const float*)d_in[5];
  const float* W3 = (const float*)d_in[6];
  const float* b3 = (const float*)d_in[7];
  (void)n_in;
  (void)out_size;
  (void)ws_size;

  const int B = in_sizes[0] / 8;  // 65536
  const int total = 2 * B;        // 131072

  char* ws = (char*)d_ws;
  size_t off = 0;
  auto carve = [&](size_t bytes) -> void* {
    off = (off + 255) & ~(size_t)255;
    void* p = ws + off;
    off += bytes;
    return p;
  };
  float* hz = (float*)carve((size_t)total * 16 * 4);        // 8.4 MB
  float* P = (float*)carve((size_t)512 * 32768 * 4);        // 67.1 MB
  float* Q = (float*)carve((size_t)2 * 8 * 3 * 16384 * 4);  // 3.1 MB
  float* scalars = (float*)carve(256);  // [0]=sumsq(A), [1]=sumsq(A^2)
  float* AR = (float*)carve(256 * 256 * 4);
  float* AI = (float*)carve(256 * 256 * 4);
  float* XR = (float*)carve(256 * 256 * 4);
  float* XI = (float*)carve(256 * 256 * 4);
  float* YR = (float*)carve(256 * 256 * 4);
  float* YI = (float*)carve(256 * 256 * 4);
  float* ZR = (float*)carve(256 * 256 * 4);
  float* ZI = (float*)carve(256 * 256 * 4);

  k_mlp<<<(total + 255) / 256, 256, 0, stream>>>(
      x1, x0, W1, b1, W2, b2, W3, b3, hz, B, scalars, (float*)d_out);
  k_gemm_f<<<512, 512, 0, stream>>>(hz, P);
  k_reduce1<<<dim3(128, 3, 8), 128, 0, stream>>>(P, Q);
  k_reduce2<<<dim3(128, 3), 128, 0, stream>>>(Q, AR, AI, scalars,
                                              1.0f / (256.0f * (float)B));

  // NS schedule (R9-calibrated, absmax 1.22e-4 vs 3.32e-4 threshold; err
  // model ~9.4/M^2 with M=278 — do NOT shorten):
  // 1x clamp(1.5-NS, rescaled, raw-A norm-folded) + 6x (2x - x^3)
  // + 4x (1.5-NS); trace fused into the last update. Multi-dispatch chain
  // (~5-6 us/launch) beats any gfx950 grid-sync (>=20 us, R10/R11).
  const int NIT = 11;
  float *cR = AR, *cI = AI, *nR = XR, *nI = XI;
  for (int it = 0; it < NIT; it++) {
    int mode = (it == 0) ? 0 : (it <= 6 ? 1 : 2);
    int fin = (it == NIT - 1) ? 1 : 0;
    k_csq<<<256, 1024, 0, stream>>>(cR, cI, YR, YI, scalars + 1, it == 0);
    k_cupd<<<256, 1024, 0, stream>>>(cR, cI, YR, YI, nR, nI, scalars, mode, AR,
                                     AI, (float*)d_out, fin);
    if (it == 0) {
      cR = XR; cI = XI; nR = ZR; nI = ZI;
    } else {
      std::swap(cR, nR);
      std::swap(cI, nI);
    }
  }
}